// Round 10
// baseline (173.710 us; speedup 1.0000x reference)
//
#include <hip/hip_runtime.h>
#include <hip/hip_bf16.h>
#include <stdint.h>

typedef __bf16 bf16;
typedef __bf16 bf16x4 __attribute__((ext_vector_type(4)));
typedef __bf16 bf16x8 __attribute__((ext_vector_type(8)));
typedef float f32x4 __attribute__((ext_vector_type(4)));
typedef float f32x16 __attribute__((ext_vector_type(16)));

#define GLDS16(g, l) __builtin_amdgcn_global_load_lds( \
    (const __attribute__((address_space(1))) void*)(g), \
    (__attribute__((address_space(3))) void*)(l), 16, 0, 0)

static constexpr int S = 2048;

// ---- fused f32->bf16 convert (x + 4 weights) + RoPE cos/sin table build ----
__global__ __launch_bounds__(256) void cvt_all(const float* __restrict__ x,
                                               const float* __restrict__ wq,
                                               const float* __restrict__ wk,
                                               const float* __restrict__ wv,
                                               const float* __restrict__ wo,
                                               const int* __restrict__ tp,
                                               bf16* __restrict__ xb,
                                               bf16* __restrict__ wqkvb,
                                               bf16* __restrict__ wob,
                                               bf16* __restrict__ tabc,
                                               bf16* __restrict__ tabs) {
  const int bid = blockIdx.x;
  if (bid >= 6144) {   // RoPE table: 8192 rows x 32 pairs
    int idx = (bid - 6144) * 256 + threadIdx.x;   // 0..262143
    int row = idx >> 5, pp = idx & 31;
    float p = (float)tp[row];
    float ang = p * exp2f((float)pp * -0.4152410118609203f);
    float sn, cs;
    sincosf(ang, &sn, &cs);
    tabc[idx] = (bf16)cs;
    tabs[idx] = (bf16)sn;
    return;
  }
  const float* src;
  bf16* dst;
  int i;
  if (bid < 4096) {            // x: 1,048,576 groups of 8
    src = x; dst = xb; i = bid * 256 + threadIdx.x;
  } else {                     // weights: 131,072 groups each
    int w = (bid - 4096) >> 9;
    i = ((bid - 4096) & 511) * 256 + threadIdx.x;
    src = (w == 0) ? wq : (w == 1) ? wk : (w == 2) ? wv : wo;
    dst = (w == 3) ? wob : wqkvb + (size_t)w * 1048576;
  }
  const float4* p = (const float4*)src + (size_t)i * 2;
  float4 a = p[0], b = p[1];
  bf16x8 o;
  o[0] = (bf16)a.x; o[1] = (bf16)a.y; o[2] = (bf16)a.z; o[3] = (bf16)a.w;
  o[4] = (bf16)b.x; o[5] = (bf16)b.y; o[6] = (bf16)b.z; o[7] = (bf16)b.w;
  *((bf16x8*)dst + i) = o;
}

// ------- NT GEMM, 128x128 tile, 2 fat waves (128x64 each), 32x32x16 --------
// LDS-read traffic per FLOP cut 2x vs 4x(64x64) thin waves: 12 ds_read_b128
// per wave-step serve 524 kFLOP (43.7 FLOP/B) -> LDS no longer the binding
// pipe; MFMA 32x32x16 (2382 TF ceiling). 3-ring BK=32 staging, vmcnt(16),
// 3 blocks/CU (48 KB). Swizzle chunk^((r>>1)^(r>>3))&3 on both GLDS source
// and read side (conflict-free 32-row fragment reads).
// MODE 0 (QKV, grid 64x24): bn<8 q, bn<16 k (table-RoPE, LDS-bounce stores);
//   bn>=16 v computed as W.x^T -> [b,h,dd,s] coalesced rows.
// MODE 2 (wo, grid 64x8): f32 direct stores to [m][1024].
template <int MODE>
__global__ __launch_bounds__(128, 2) void gemm_k(const bf16* __restrict__ xA,
                                                 const bf16* __restrict__ wB,
                                                 const bf16* __restrict__ tabc,
                                                 const bf16* __restrict__ tabs,
                                                 bf16* __restrict__ oq,
                                                 bf16* __restrict__ ok,
                                                 bf16* __restrict__ ov,
                                                 float* __restrict__ outf) {
  constexpr int K = 1024;
  __shared__ __align__(16) char lds[49152];
  const int t = threadIdx.x, l = t & 63, w = t >> 6;   // 2 waves
  const int bm = blockIdx.x, bn = blockIdx.y;
  const int l5 = l & 31, hi = l >> 5;

  // ---- block decode
  int sel, tA, tB;
  const bf16 *Ap, *Bp;
  if (MODE == 0) {
    if (bn < 16) {
      sel = bn >> 3;                                 // 0=q, 1=k
      tA = bm;                                       // s-tile 0..63
      tB = bn & 7;                                   // col-tile 0..7
      Ap = xA + (size_t)tA * 128 * K;
      Bp = wB + (size_t)(sel * 1024 + tB * 128) * K;
    } else {
      sel = 2;
      tA = bn - 16;                                  // dd-tile 0..7
      tB = bm;                                       // s-tile 0..63
      Ap = wB + (size_t)(2048 + tA * 128) * K;       // A = wv rows (dd)
      Bp = xA + (size_t)tB * 128 * K;                // B = x rows (s)
    }
  } else {
    sel = 3;
    tA = bm; tB = bn;
    Ap = xA + (size_t)tA * 128 * K;
    Bp = wB + (size_t)tB * 128 * K;
  }

  // ---- staging: per wave 4 row-groups x (A,B) = 8 GLDS16/step
  // lane l -> row g*16 + (l>>2), phys chunk l&3; logical = phys ^ swz(row)
  // swz(r) = ((r>>1)^(r>>3))&3; for r = w*64+g*16+(l>>2):
  //   (r>>1)&3 = (l>>3)&3 ; (r>>3)&3 = 2*(g&1) + ((l>>5)&1)
  const int lrow = l >> 2;
  const int swe = (((l >> 3) & 3) ^ ((l >> 5) & 1));
  const int cs_e = ((l & 3) ^ swe) * 8;          // g even
  const int cs_o = ((l & 3) ^ swe ^ 2) * 8;      // g odd
  const bf16* aS = Ap + (size_t)(w * 64 + lrow) * K;
  const bf16* bS = Bp + (size_t)(w * 64 + lrow) * K;

  auto stage = [&](int kt, char* base) {
#pragma unroll
    for (int g = 0; g < 4; g++) {
      const int cs = (g & 1) ? cs_o : cs_e;
      GLDS16(aS + (size_t)(g * 16) * K + kt + cs, base + (w * 64 + g * 16) * 64);
      GLDS16(bS + (size_t)(g * 16) * K + kt + cs,
             base + 8192 + (w * 64 + g * 16) * 64);
    }
  };

  // ---- loop-invariant fragment read offsets (32x32x16 layout:
  // row = l&31 within tile, 16B chunk = 2*kc + (l>>5), ^ swz(row))
  int offA[4][2], offB[2][2];
#pragma unroll
  for (int mi = 0; mi < 4; mi++)
#pragma unroll
    for (int kc = 0; kc < 2; kc++) {
      int ra = mi * 32 + l5;
      int swr = ((ra >> 1) ^ (ra >> 3)) & 3;
      offA[mi][kc] = ra * 64 + (((2 * kc + hi) ^ swr) * 16);
    }
#pragma unroll
  for (int ni = 0; ni < 2; ni++)
#pragma unroll
    for (int kc = 0; kc < 2; kc++) {
      int rb = w * 64 + ni * 32 + l5;
      int swr = ((rb >> 1) ^ (rb >> 3)) & 3;
      offB[ni][kc] = 8192 + rb * 64 + (((2 * kc + hi) ^ swr) * 16);
    }

  f32x16 acc[4][2] = {};

  char* cur = lds;
  char* nxt = lds + 16384;
  char* ovr = lds + 32768;
  stage(0, cur);
  stage(32, nxt);
#pragma unroll 1
  for (int t_ = 0; t_ < 32; ++t_) {
    if (t_ + 2 < 32) {
      stage((t_ + 2) * 32, ovr);
      asm volatile("s_waitcnt vmcnt(16)" ::: "memory");
    } else if (t_ + 1 < 32) {
      asm volatile("s_waitcnt vmcnt(8)" ::: "memory");
    } else {
      asm volatile("s_waitcnt vmcnt(0)" ::: "memory");
    }
    __builtin_amdgcn_s_barrier();
    __builtin_amdgcn_sched_barrier(0);

    bf16x8 af[4][2], bg[2][2];
#pragma unroll
    for (int mi = 0; mi < 4; mi++)
#pragma unroll
      for (int kc = 0; kc < 2; kc++)
        af[mi][kc] = *(const bf16x8*)(cur + offA[mi][kc]);
#pragma unroll
    for (int ni = 0; ni < 2; ni++)
#pragma unroll
      for (int kc = 0; kc < 2; kc++)
        bg[ni][kc] = *(const bf16x8*)(cur + offB[ni][kc]);

    __builtin_amdgcn_s_setprio(1);
#pragma unroll
    for (int mi = 0; mi < 4; mi++)
#pragma unroll
      for (int ni = 0; ni < 2; ni++)
#pragma unroll
        for (int kc = 0; kc < 2; kc++)
          acc[mi][ni] = __builtin_amdgcn_mfma_f32_32x32x16_bf16(
              af[mi][kc], bg[ni][kc], acc[mi][ni], 0, 0, 0);
    __builtin_amdgcn_s_setprio(0);
    asm volatile("s_waitcnt lgkmcnt(0)" ::: "memory");
    __builtin_amdgcn_sched_barrier(0);
    __builtin_amdgcn_s_barrier();
    char* tmp = cur; cur = nxt; nxt = ovr; ovr = tmp;
  }

  // C layout per 32x32 tile: row = (r&3)+8*(r>>2)+4*hi, col = l&31
  if (MODE == 2) {   // wo: direct f32 stores (128 B contiguous per instr)
#pragma unroll
    for (int mi = 0; mi < 4; mi++)
#pragma unroll
      for (int ni = 0; ni < 2; ni++)
#pragma unroll
        for (int r = 0; r < 16; r++) {
          int gm = tA * 128 + mi * 32 + (r & 3) + 8 * (r >> 2) + 4 * hi;
          int gn = tB * 128 + w * 64 + ni * 32 + l5;
          outf[(size_t)gm * 1024 + gn] = acc[mi][ni][r];
        }
    return;
  }

  // ---- E1: acc -> LDS [128][136] bf16 overlay (ring is dead)
#pragma unroll
  for (int mi = 0; mi < 4; mi++)
#pragma unroll
    for (int ni = 0; ni < 2; ni++)
#pragma unroll
      for (int r = 0; r < 16; r++) {
        int row = mi * 32 + (r & 3) + 8 * (r >> 2) + 4 * hi;
        int col = w * 64 + ni * 32 + l5;
        *(bf16*)(lds + row * 272 + col * 2) = (bf16)acc[mi][ni][r];
      }
  __syncthreads();

  // ---- E2: coalesced stores; 16 lanes cover one row; RoPE via bf16 tables
#pragma unroll 2
  for (int i = 0; i < 16; ++i) {
    const int id = t + 128 * i;
    const int row = id >> 4, ch = id & 15;
    bf16x8 v8 = *(const bf16x8*)(lds + row * 272 + ch * 16);
    if (sel < 2) {
      const int m = tA * 128 + row;
      const int g = ch & 7;
      bf16x4 tc = *(const bf16x4*)(tabc + m * 32 + g * 4);
      bf16x4 tsn = *(const bf16x4*)(tabs + m * 32 + g * 4);
      bf16x8 o;
#pragma unroll
      for (int j = 0; j < 4; j++) {
        float cs = (float)tc[j], sn = (float)tsn[j];
        float e = (float)v8[2 * j], od = (float)v8[2 * j + 1];
        o[2 * j]     = (bf16)(e * cs - od * sn);
        o[2 * j + 1] = (bf16)(e * sn + od * cs);
      }
      bf16* dst = (sel == 0) ? oq : ok;
      const int h = tB * 2 + (ch >> 3);
      size_t idx = ((size_t)((m >> 11) * 16 + h) << 17) +
                   ((size_t)(m & 2047) << 6) + g * 8;
      *(bf16x8*)(dst + idx) = o;
    } else {
      const int dd = tA * 128 + row;
      const int h = dd >> 6;
      const int s0 = tB * 128 + ch * 8;
      size_t idx = ((size_t)((s0 >> 11) * 16 + h) << 17) +
                   ((size_t)(dd & 63) << 11) + (s0 & 2047);
      *(bf16x8*)(ov + idx) = v8;
    }
  }
}

// ---------------- causal flash attention, 32x32x16, 8-wave QBLK=256 ---------
// 512 blocks: one (bh, qt) each; complementary pairing for 2-blocks/CU.
// Per-half QK->softmax->PV; 3-deep circular K/V prefetch; swapped QK^T;
// sigma-permuted in-register P; no max-subtract softmax.
__global__ __launch_bounds__(512, 4) void attn_k(const bf16* __restrict__ q,
                                                 const bf16* __restrict__ k,
                                                 const bf16* __restrict__ vt,
                                                 bf16* __restrict__ att) {
  __shared__ bf16 Ks[3][4096];   // [buf][kv 64][d 64], rows XOR-swizzled
  __shared__ bf16 Vs[3][4096];   // [buf][d 64][kv 64], rows XOR-swizzled

  const int t = threadIdx.x, l = t & 63, w = t >> 6;   // w = 0..7
  const int hi2 = l >> 5, q5 = l & 31;

  const int raw = blockIdx.x;
  const int r2 = raw & 255;
  const int wg = (r2 & 7) * 32 + (r2 >> 3);      // 4 bh per XCD, L2-local
  const int bh = ((raw < 256) ? 0 : 32) + (wg >> 3);
  const int qt = (raw < 256) ? (wg & 7) : 7 - (wg & 7);

  const bf16* qb = q + (size_t)bh * S * 64;
  const bf16* kb = k + (size_t)bh * S * 64;
  const bf16* vb = vt + (size_t)bh * 64 * S;

  const int lrow = l >> 3;
  const int clog = ((l & 7) ^ (lrow & 7)) * 8;   // pre-swizzled source chunk

  auto stage = [&](int nt, int b) {
    GLDS16(kb + (size_t)(nt * 64 + w * 8 + lrow) * 64 + clog, &Ks[b][w * 512]);
    GLDS16(vb + (size_t)(w * 8 + lrow) * S + nt * 64 + clog, &Vs[b][w * 512]);
  };

  const int swz = (q5 & 7) << 4;
  int kaddr[4], vaddr[8];
#pragma unroll
  for (int c = 0; c < 4; c++)
    kaddr[c] = q5 * 128 + ((32 * c + 16 * hi2) ^ swz);
#pragma unroll
  for (int m = 0; m < 8; m++)
    vaddr[m] = q5 * 128 + ((16 * m) ^ swz) + 8 * hi2;

  const int b_ = bh >> 4, h_ = bh & 15;
  const char* KsB = (const char*)&Ks[0][0];
  const char* VsB = (const char*)&Vs[0][0];

  const int wqbase = qt * 256 + w * 32;
  const int qrow = wqbase + q5;
  bf16x8 qf[4];   // Q^T B-operand, chunk c: d = 16c+8*hi2+(0..7); scaled
#pragma unroll
  for (int c = 0; c < 4; c++) {
    bf16x8 rq = *(const bf16x8*)&qb[(size_t)qrow * 64 + 16 * c + 8 * hi2];
    bf16x8 s_;
#pragma unroll
    for (int j2 = 0; j2 < 8; j2++)
      s_[j2] = (bf16)((float)rq[j2] * 0.18033688011112042f);
    qf[c] = s_;
  }

  f32x16 acc[2] = {};
  float l_r = 0.f;
  const int nkv = 4 * qt + 4;
  const int qmaxw = wqbase + 31;

  int cur = 0, nxt = 1, ovr = 2;
  stage(0, 0);
  stage(1, 1);
#pragma unroll 1
  for (int nt = 0; nt < nkv; ++nt) {
    if (nt + 2 < nkv) {
      stage(nt + 2, ovr);
      asm volatile("s_waitcnt vmcnt(4)" ::: "memory");
    } else if (nt + 1 < nkv) {
      asm volatile("s_waitcnt vmcnt(2)" ::: "memory");
    } else {
      asm volatile("s_waitcnt vmcnt(0)" ::: "memory");
    }
    __builtin_amdgcn_s_barrier();
    __builtin_amdgcn_sched_barrier(0);

    const bool live = (64 * nt) <= qmaxw;
    if (live) {
      const int bo = cur * 8192;
      float rs = 0.f;
#pragma unroll
      for (int T = 0; T < 2; T++) {
        // S^T = K Q^T for half-tile T (kv 32T..32T+31)
        f32x16 sc = {};
        __builtin_amdgcn_s_setprio(1);
#pragma unroll
        for (int c = 0; c < 4; c++) {
          bf16x8 kf = *(const bf16x8*)(KsB + bo + T * 4096 + kaddr[c]);
          sc = __builtin_amdgcn_mfma_f32_32x32x16_bf16(kf, qf[c], sc, 0, 0, 0);
        }
        __builtin_amdgcn_s_setprio(0);

        if (64 * nt + 32 * T + 31 > wqbase) {   // causal mask
#pragma unroll
          for (int r = 0; r < 16; r++) {
            int kvg = 64 * nt + 32 * T + (r & 3) + 8 * (r >> 2) + 4 * hi2;
            if (kvg > qrow) sc[r] = -1e30f;
          }
        }

        // softmax (no max-subtract) + pack P for this half
        bf16x8 pa0, pa1;
#pragma unroll
        for (int r = 0; r < 8; r++) {
          float p0 = __builtin_amdgcn_exp2f(sc[r]);
          float p1 = __builtin_amdgcn_exp2f(sc[8 + r]);
          rs += p0 + p1;
          pa0[r] = (bf16)p0;
          pa1[r] = (bf16)p1;
        }

        // O += P'V for this half: c = 2T (pa0), 2T+1 (pa1)
        __builtin_amdgcn_s_setprio(1);
#pragma unroll
        for (int dt = 0; dt < 2; dt++) {
          bf16x4 v0 = *(const bf16x4*)(VsB + bo + dt * 4096 + vaddr[4 * T]);
          bf16x4 v1 = *(const bf16x4*)(VsB + bo + dt * 4096 + vaddr[4 * T + 1]);
          bf16x8 bv;
#pragma unroll
          for (int j2 = 0; j2 < 4; j2++) { bv[j2] = v0[j2]; bv[4 + j2] = v1[j2]; }
          acc[dt] = __builtin_amdgcn_mfma_f32_32x32x16_bf16(pa0, bv, acc[dt], 0, 0, 0);
          v0 = *(const bf16x4*)(VsB + bo + dt * 4096 + vaddr[4 * T + 2]);
          v1 = *(const bf16x4*)(VsB + bo + dt * 4096 + vaddr[4 * T + 3]);
#pragma unroll
          for (int j2 = 0; j2 < 4; j2++) { bv[j2] = v0[j2]; bv[4 + j2] = v1[j2]; }
          acc[dt] = __builtin_amdgcn_mfma_f32_32x32x16_bf16(pa1, bv, acc[dt], 0, 0, 0);
        }
        __builtin_amdgcn_s_setprio(0);
      }
      rs += __shfl_xor(rs, 32);
      l_r += rs;
    }

    asm volatile("s_waitcnt lgkmcnt(0)" ::: "memory");
    __builtin_amdgcn_sched_barrier(0);
    __builtin_amdgcn_s_barrier();
    int t3 = cur; cur = nxt; nxt = ovr; ovr = t3;
  }

  // epilogue: O row = qt*256 + w*32 + rmap(r,hi2), col d = 32dt + q5
  float linv = 1.f / l_r;
#pragma unroll
  for (int r = 0; r < 16; r++) {
    int rmap = (r & 3) + 8 * (r >> 2) + 4 * hi2;
    float li = __shfl(linv, rmap);
    int rowq = wqbase + rmap;
    size_t rb = ((size_t)(b_ * S + rowq) << 10) + h_ * 64 + q5;
#pragma unroll
    for (int dt = 0; dt < 2; dt++)
      att[rb + 32 * dt] = (bf16)(acc[dt][r] * li);
  }
}

extern "C" void kernel_launch(void* const* d_in, const int* in_sizes, int n_in,
                              void* d_out, int out_size, void* d_ws, size_t ws_size,
                              hipStream_t stream) {
  const float* x  = (const float*)d_in[0];
  const int* tp   = (const int*)d_in[1];
  const float* wq = (const float*)d_in[2];
  const float* wk = (const float*)d_in[3];
  const float* wv = (const float*)d_in[4];
  const float* wo = (const float*)d_in[5];
  float* out = (float*)d_out;

  char* ws = (char*)d_ws;
  const size_t TEN = 16777216;  // 8192*1024*2 bytes
  bf16* x_bf    = (bf16*)(ws);
  bf16* q_bf    = (bf16*)(ws + TEN);
  bf16* k_bf    = (bf16*)(ws + 2 * TEN);
  bf16* v_bf    = (bf16*)(ws + 3 * TEN);
  bf16* wqkv_bf = (bf16*)(ws + 4 * TEN);          // 3072x1024 = 6MB
  bf16* wo_bf   = wqkv_bf + 3 * 1048576;          // 2MB
  bf16* tabc    = wo_bf + 1048576;                // 512KB (8192x32 bf16)
  bf16* tabs    = tabc + 262144;                  // 512KB
  bf16* att_bf  = x_bf;   // alias: x_bf dead after QKV projection

  cvt_all<<<7168, 256, 0, stream>>>(x, wq, wk, wv, wo, tp, x_bf, wqkv_bf,
                                    wo_bf, tabc, tabs);

  dim3 gq(64, 24);
  gemm_k<0><<<gq, 128, 0, stream>>>(x_bf, wqkv_bf, tabc, tabs, q_bf, k_bf,
                                    v_bf, nullptr);

  attn_k<<<512, 512, 0, stream>>>(q_bf, k_bf, v_bf, att_bf);

  dim3 go(64, 8);
  gemm_k<2><<<go, 128, 0, stream>>>(att_bf, wo_bf, nullptr, nullptr, nullptr,
                                    nullptr, nullptr, out);
}

// Round 11
// 161.882 us; speedup vs baseline: 1.0731x; 1.0731x over previous
//
#include <hip/hip_runtime.h>
#include <hip/hip_bf16.h>
#include <stdint.h>

typedef __bf16 bf16;
typedef __bf16 bf16x4 __attribute__((ext_vector_type(4)));
typedef __bf16 bf16x8 __attribute__((ext_vector_type(8)));
typedef float f32x4 __attribute__((ext_vector_type(4)));
typedef float f32x16 __attribute__((ext_vector_type(16)));

#define GLDS16(g, l) __builtin_amdgcn_global_load_lds( \
    (const __attribute__((address_space(1))) void*)(g), \
    (__attribute__((address_space(3))) void*)(l), 16, 0, 0)

static constexpr int S = 2048;

// ---- fused f32->bf16 convert (x + 4 weights) + RoPE cos/sin table build ----
__global__ __launch_bounds__(256) void cvt_all(const float* __restrict__ x,
                                               const float* __restrict__ wq,
                                               const float* __restrict__ wk,
                                               const float* __restrict__ wv,
                                               const float* __restrict__ wo,
                                               const int* __restrict__ tp,
                                               bf16* __restrict__ xb,
                                               bf16* __restrict__ wqkvb,
                                               bf16* __restrict__ wob,
                                               bf16* __restrict__ tabc,
                                               bf16* __restrict__ tabs) {
  const int bid = blockIdx.x;
  if (bid >= 6144) {   // RoPE table: 8192 rows x 32 pairs
    int idx = (bid - 6144) * 256 + threadIdx.x;   // 0..262143
    int row = idx >> 5, pp = idx & 31;
    float p = (float)tp[row];
    float ang = p * exp2f((float)pp * -0.4152410118609203f);
    float sn, cs;
    sincosf(ang, &sn, &cs);
    tabc[idx] = (bf16)cs;
    tabs[idx] = (bf16)sn;
    return;
  }
  const float* src;
  bf16* dst;
  int i;
  if (bid < 4096) {            // x: 1,048,576 groups of 8
    src = x; dst = xb; i = bid * 256 + threadIdx.x;
  } else {                     // weights: 131,072 groups each
    int w = (bid - 4096) >> 9;
    i = ((bid - 4096) & 511) * 256 + threadIdx.x;
    src = (w == 0) ? wq : (w == 1) ? wk : (w == 2) ? wv : wo;
    dst = (w == 3) ? wob : wqkvb + (size_t)w * 1048576;
  }
  const float4* p = (const float4*)src + (size_t)i * 2;
  float4 a = p[0], b = p[1];
  bf16x8 o;
  o[0] = (bf16)a.x; o[1] = (bf16)a.y; o[2] = (bf16)a.z; o[3] = (bf16)a.w;
  o[4] = (bf16)b.x; o[5] = (bf16)b.y; o[6] = (bf16)b.z; o[7] = (bf16)b.w;
  *((bf16x8*)dst + i) = o;
}

// ------- QKV GEMM: 256x256 tile, BK=64, 8 waves (2Mx4N, 128x64/wave), -------
// 4-phase/K-tile interleave, dbuf 128KB, 1 block/CU, counted vmcnt(4).
// Phase p: {ds_read subtile || stage 1 freed region -> barrier -> lgkm(0) ->
// setprio 16 MFMA (one C-quadrant) -> barrier}. Quadrant order M0N0, M0N1,
// M1N1, M1N0 frees A rows {0-63,128-191} after ph2 and B cols ==32..63(mod 64)
// after ph3 -> staging targets only freed regions (WAR-safe via barriers).
// vmcnt(4) once per K-tile (before ph4's closing barrier) confirms all data
// tile T+1 reads while keeping 4 loads in flight. Rows chunk^(row&7) swizzled.
// bn<4 -> q, <8 -> k (table-RoPE epilogue), >=8 -> v = W.x^T -> [b,h,dd,s].
__global__ __launch_bounds__(512, 2) void gemm8p(const bf16* __restrict__ xA,
                                                 const bf16* __restrict__ wB,
                                                 const bf16* __restrict__ tabc,
                                                 const bf16* __restrict__ tabs,
                                                 bf16* __restrict__ oq,
                                                 bf16* __restrict__ ok,
                                                 bf16* __restrict__ ov) {
  constexpr int K = 1024;
  __shared__ __align__(16) char lds[131072];
  const int t = threadIdx.x, l = t & 63, w = t >> 6;   // 8 waves
  const int wm = w >> 2, wn = w & 3;                   // 2M x 4N
  const int bm = blockIdx.x, bn = blockIdx.y;

  int sel;
  const bf16 *Ap, *Bp;
  if (bn < 8) {
    sel = bn >> 2;                                  // 0=q, 1=k
    Ap = xA + (size_t)bm * 256 * K;
    Bp = wB + (size_t)bn * 256 * K;
  } else {
    sel = 2;                                        // v: A = wv rows (dd)
    Ap = wB + (size_t)bn * 256 * K;
    Bp = xA + (size_t)bm * 256 * K;
  }

  // ---- staging lanes: 1KB per GLDS16 (8 rows x 128B); pre-swizzled source
  const int lr8 = l >> 3;
  const int clog = ((l & 7) ^ (lr8 & 7)) * 8;
  const int rsA0 = wm * 128 + (wn * 2 + 0) * 8;   // A slice rows (j=0)
  const int rsA1 = wm * 128 + (wn * 2 + 1) * 8;   // (j=1)
  const int c0B0 = (w >> 1) * 64 + ((w & 1) * 2 + 0) * 8;
  const int c0B1 = (w >> 1) * 64 + ((w & 1) * 2 + 1) * 8;

  auto stA = [&](int T, int rs) {
    GLDS16(Ap + (size_t)(rs + lr8) * K + T * 64 + clog,
           lds + (T & 1) * 65536 + rs * 128);
  };
  auto stB = [&](int T, int c0) {
    GLDS16(Bp + (size_t)(c0 + lr8) * K + T * 64 + clog,
           lds + (T & 1) * 65536 + 32768 + c0 * 128);
  };

  // ---- fragment read bases (row&7 == l&7 for all frags -> 2 chunk offsets)
  const int sw0 = (((l >> 4)) ^ (l & 7)) * 16;       // ks=0
  const int sw1 = ((4 + (l >> 4)) ^ (l & 7)) * 16;   // ks=1
  const int rowA = wm * 128 + (l & 15);
  const int colB = wn * 64 + (l & 15);
  const int baseA0 = rowA * 128 + sw0, baseA1 = rowA * 128 + sw1;
  const int baseB0 = 32768 + colB * 128 + sw0, baseB1 = 32768 + colB * 128 + sw1;

  f32x4 acc[8][4] = {};

  // ---- prologue: tile0 all 4 regions, then tile1 {A1,B1} (newest 4 allowed)
  stA(0, rsA0); stA(0, rsA1);                 // A1(0)
  stB(0, 32 + c0B0); stB(0, 32 + c0B1);       // B1(0)
  stA(0, 64 + rsA0); stA(0, 64 + rsA1);       // A2(0)
  stB(0, c0B0); stB(0, c0B1);                 // B2(0)
  stA(1, rsA0); stA(1, rsA1);                 // A1(1)
  stB(1, 32 + c0B0); stB(1, 32 + c0B1);       // B1(1)
  asm volatile("s_waitcnt vmcnt(4)" ::: "memory");
  __builtin_amdgcn_s_barrier();

#pragma unroll 1
  for (int T = 0; T < 16; ++T) {
    const char* bb = lds + (T & 1) * 65536;
    bf16x8 a0[4][2], a1[4][2], b0[2][2], b1[2][2];

    // ---- ph1: read A-lo (8) + B-lo (4); stage A2(T+1); MFMA Q(lo,lo)
#pragma unroll
    for (int mi = 0; mi < 4; mi++) {
      a0[mi][0] = *(const bf16x8*)(bb + baseA0 + mi * 2048);
      a0[mi][1] = *(const bf16x8*)(bb + baseA1 + mi * 2048);
    }
#pragma unroll
    for (int ni = 0; ni < 2; ni++) {
      b0[ni][0] = *(const bf16x8*)(bb + baseB0 + ni * 2048);
      b0[ni][1] = *(const bf16x8*)(bb + baseB1 + ni * 2048);
    }
    if (T + 1 < 16) { stA(T + 1, 64 + rsA0); stA(T + 1, 64 + rsA1); }
    __builtin_amdgcn_s_barrier();
    asm volatile("s_waitcnt lgkmcnt(0)" ::: "memory");
    __builtin_amdgcn_sched_barrier(0);
    __builtin_amdgcn_s_setprio(1);
#pragma unroll
    for (int mi = 0; mi < 4; mi++)
#pragma unroll
      for (int ni = 0; ni < 2; ni++)
#pragma unroll
        for (int ks = 0; ks < 2; ks++)
          acc[mi][ni] = __builtin_amdgcn_mfma_f32_16x16x32_bf16(
              a0[mi][ks], b0[ni][ks], acc[mi][ni], 0, 0, 0);
    __builtin_amdgcn_s_setprio(0);
    __builtin_amdgcn_s_barrier();

    // ---- ph2: read B-hi (4); stage B2(T+1); MFMA Q(lo,hi)
#pragma unroll
    for (int ni = 0; ni < 2; ni++) {
      b1[ni][0] = *(const bf16x8*)(bb + baseB0 + (2 + ni) * 2048);
      b1[ni][1] = *(const bf16x8*)(bb + baseB1 + (2 + ni) * 2048);
    }
    if (T + 1 < 16) { stB(T + 1, c0B0); stB(T + 1, c0B1); }
    __builtin_amdgcn_s_barrier();
    asm volatile("s_waitcnt lgkmcnt(0)" ::: "memory");
    __builtin_amdgcn_sched_barrier(0);
    __builtin_amdgcn_s_setprio(1);
#pragma unroll
    for (int mi = 0; mi < 4; mi++)
#pragma unroll
      for (int ni = 0; ni < 2; ni++)
#pragma unroll
        for (int ks = 0; ks < 2; ks++)
          acc[mi][2 + ni] = __builtin_amdgcn_mfma_f32_16x16x32_bf16(
              a0[mi][ks], b1[ni][ks], acc[mi][2 + ni], 0, 0, 0);
    __builtin_amdgcn_s_setprio(0);
    __builtin_amdgcn_s_barrier();

    // ---- ph3: read A-hi (8); stage A1(T+2); MFMA Q(hi,hi)
#pragma unroll
    for (int mi = 0; mi < 4; mi++) {
      a1[mi][0] = *(const bf16x8*)(bb + baseA0 + (4 + mi) * 2048);
      a1[mi][1] = *(const bf16x8*)(bb + baseA1 + (4 + mi) * 2048);
    }
    if (T + 2 < 16) { stA(T + 2, rsA0); stA(T + 2, rsA1); }
    __builtin_amdgcn_s_barrier();
    asm volatile("s_waitcnt lgkmcnt(0)" ::: "memory");
    __builtin_amdgcn_sched_barrier(0);
    __builtin_amdgcn_s_setprio(1);
#pragma unroll
    for (int mi = 0; mi < 4; mi++)
#pragma unroll
      for (int ni = 0; ni < 2; ni++)
#pragma unroll
        for (int ks = 0; ks < 2; ks++)
          acc[4 + mi][2 + ni] = __builtin_amdgcn_mfma_f32_16x16x32_bf16(
              a1[mi][ks], b1[ni][ks], acc[4 + mi][2 + ni], 0, 0, 0);
    __builtin_amdgcn_s_setprio(0);
    __builtin_amdgcn_s_barrier();

    // ---- ph4: stage B1(T+2); MFMA Q(hi,lo) (held regs); counted vmcnt
    if (T + 2 < 16) { stB(T + 2, 32 + c0B0); stB(T + 2, 32 + c0B1); }
    __builtin_amdgcn_s_setprio(1);
#pragma unroll
    for (int mi = 0; mi < 4; mi++)
#pragma unroll
      for (int ni = 0; ni < 2; ni++)
#pragma unroll
        for (int ks = 0; ks < 2; ks++)
          acc[4 + mi][ni] = __builtin_amdgcn_mfma_f32_16x16x32_bf16(
              a1[mi][ks], b0[ni][ks], acc[4 + mi][ni], 0, 0, 0);
    __builtin_amdgcn_s_setprio(0);
    if (T < 14) {
      asm volatile("s_waitcnt vmcnt(4)" ::: "memory");
    } else {
      asm volatile("s_waitcnt vmcnt(0)" ::: "memory");
    }
    __builtin_amdgcn_s_barrier();
  }

  __syncthreads();

  // ---- epilogue: two half-passes via overlay (128 rows x 528B = 67.5 KB)
#pragma unroll 1
  for (int pass = 0; pass < 2; ++pass) {
    if (wm == pass) {
#pragma unroll
      for (int mi = 0; mi < 8; mi++)
#pragma unroll
        for (int ni = 0; ni < 4; ni++)
#pragma unroll
          for (int r = 0; r < 4; r++) {
            int row = mi * 16 + (l >> 4) * 4 + r;       // 0..127
            int col = wn * 64 + ni * 16 + (l & 15);     // 0..255
            *(bf16*)(lds + row * 528 + col * 2) = (bf16)acc[mi][ni][r];
          }
    }
    __syncthreads();
#pragma unroll 2
    for (int i = 0; i < 8; ++i) {
      int id = t + 512 * i;
      int rloc = id >> 5, ch = id & 31;
      int row = pass * 128 + rloc;
      bf16x8 v8 = *(const bf16x8*)(lds + rloc * 528 + ch * 16);
      if (sel < 2) {
        const int m = bm * 256 + row;
        const int g = ch & 7;
        bf16x4 tc = *(const bf16x4*)(tabc + m * 32 + g * 4);
        bf16x4 tsn = *(const bf16x4*)(tabs + m * 32 + g * 4);
        bf16x8 o;
#pragma unroll
        for (int j = 0; j < 4; j++) {
          float cs = (float)tc[j], sn = (float)tsn[j];
          float e = (float)v8[2 * j], od = (float)v8[2 * j + 1];
          o[2 * j]     = (bf16)(e * cs - od * sn);
          o[2 * j + 1] = (bf16)(e * sn + od * cs);
        }
        bf16* dst = (sel == 0) ? oq : ok;
        const int h = (bn & 3) * 4 + (ch >> 3);
        size_t idx = ((size_t)((m >> 11) * 16 + h) << 17) +
                     ((size_t)(m & 2047) << 6) + g * 8;
        *(bf16x8*)(dst + idx) = o;
      } else {
        const int dd = (bn - 8) * 256 + row;
        const int h = dd >> 6;
        const int s0 = bm * 256 + ch * 8;
        size_t idx = ((size_t)((s0 >> 11) * 16 + h) << 17) +
                     ((size_t)(dd & 63) << 11) + (s0 & 2047);
        *(bf16x8*)(ov + idx) = v8;
      }
    }
    __syncthreads();
  }
}

// ---------------- wo GEMM (r9-proven): 128x128, BK=32, 3 blocks/CU ----------
__global__ __launch_bounds__(256, 3) void gemm_wo(const bf16* __restrict__ xA,
                                                  const bf16* __restrict__ wB,
                                                  float* __restrict__ outf) {
  constexpr int K = 1024;
  __shared__ __align__(16) char lds[49152];
  const int t = threadIdx.x, l = t & 63, wid = t >> 6;
  const int wm = wid >> 1, wn = wid & 1;
  const int bm = blockIdx.x, bn = blockIdx.y;

  const bf16* Ap = xA + (size_t)bm * 128 * K;
  const bf16* Bp = wB + (size_t)bn * 128 * K;

  const int lrow = l >> 2;
  const int csrc = ((l & 3) ^ ((l >> 3) & 3)) * 8;
  const bf16* aS = Ap + (size_t)(wid * 32 + lrow) * K + csrc;
  const bf16* bS = Bp + (size_t)(wid * 32 + lrow) * K + csrc;

  auto stage = [&](int kt, char* base) {
    GLDS16(aS + kt, base + (wid * 32) * 64);
    GLDS16(aS + (size_t)16 * K + kt, base + (wid * 32 + 16) * 64);
    GLDS16(bS + kt, base + 8192 + (wid * 32) * 64);
    GLDS16(bS + (size_t)16 * K + kt, base + 8192 + (wid * 32 + 16) * 64);
  };

  int offA[4], offB[4];
#pragma unroll
  for (int f = 0; f < 4; f++) {
    int ra = wm * 64 + f * 16 + (l & 15);
    offA[f] = ra * 64 + (((l >> 4) ^ ((ra >> 1) & 3)) * 16);
    int rb = wn * 64 + f * 16 + (l & 15);
    offB[f] = 8192 + rb * 64 + (((l >> 4) ^ ((rb >> 1) & 3)) * 16);
  }

  f32x4 acc[4][4] = {};

  char* cur = lds;
  char* nxt = lds + 16384;
  char* ovr = lds + 32768;
  stage(0, cur);
  stage(32, nxt);
#pragma unroll 1
  for (int t_ = 0; t_ < 32; ++t_) {
    if (t_ + 2 < 32) {
      stage((t_ + 2) * 32, ovr);
      asm volatile("s_waitcnt vmcnt(8)" ::: "memory");
    } else if (t_ + 1 < 32) {
      asm volatile("s_waitcnt vmcnt(4)" ::: "memory");
    } else {
      asm volatile("s_waitcnt vmcnt(0)" ::: "memory");
    }
    __builtin_amdgcn_s_barrier();
    __builtin_amdgcn_sched_barrier(0);

    bf16x8 af[4], bg[4];
#pragma unroll
    for (int f = 0; f < 4; f++) {
      af[f] = *(const bf16x8*)(cur + offA[f]);
      bg[f] = *(const bf16x8*)(cur + offB[f]);
    }
    __builtin_amdgcn_s_setprio(1);
#pragma unroll
    for (int mi = 0; mi < 4; mi++)
#pragma unroll
      for (int ni = 0; ni < 4; ni++)
        acc[mi][ni] = __builtin_amdgcn_mfma_f32_16x16x32_bf16(
            af[mi], bg[ni], acc[mi][ni], 0, 0, 0);
    __builtin_amdgcn_s_setprio(0);
    asm volatile("s_waitcnt lgkmcnt(0)" ::: "memory");
    __builtin_amdgcn_sched_barrier(0);
    __builtin_amdgcn_s_barrier();
    char* tmp = cur; cur = nxt; nxt = ovr; ovr = tmp;
  }

  const int rbase = bm * 128 + wm * 64 + (l >> 4) * 4;
  const int cbase = bn * 128 + wn * 64 + (l & 15);
#pragma unroll
  for (int mi = 0; mi < 4; mi++)
#pragma unroll
    for (int ni = 0; ni < 4; ni++)
#pragma unroll
      for (int r = 0; r < 4; r++)
        outf[(size_t)(rbase + mi * 16 + r) * 1024 + cbase + ni * 16] =
            acc[mi][ni][r];
}

// ---------------- causal flash attention (r9-proven) ------------------------
__global__ __launch_bounds__(512, 4) void attn_k(const bf16* __restrict__ q,
                                                 const bf16* __restrict__ k,
                                                 const bf16* __restrict__ vt,
                                                 bf16* __restrict__ att) {
  __shared__ bf16 Ks[3][4096];
  __shared__ bf16 Vs[3][4096];

  const int t = threadIdx.x, l = t & 63, w = t >> 6;
  const int hi2 = l >> 5, q5 = l & 31;

  const int raw = blockIdx.x;
  const int r2 = raw & 255;
  const int wg = (r2 & 7) * 32 + (r2 >> 3);
  const int bh = ((raw < 256) ? 0 : 32) + (wg >> 3);
  const int qt = (raw < 256) ? (wg & 7) : 7 - (wg & 7);

  const bf16* qb = q + (size_t)bh * S * 64;
  const bf16* kb = k + (size_t)bh * S * 64;
  const bf16* vb = vt + (size_t)bh * 64 * S;

  const int lrow = l >> 3;
  const int clog = ((l & 7) ^ (lrow & 7)) * 8;

  auto stage = [&](int nt, int b) {
    GLDS16(kb + (size_t)(nt * 64 + w * 8 + lrow) * 64 + clog, &Ks[b][w * 512]);
    GLDS16(vb + (size_t)(w * 8 + lrow) * S + nt * 64 + clog, &Vs[b][w * 512]);
  };

  const int swz = (q5 & 7) << 4;
  int kaddr[4], vaddr[8];
#pragma unroll
  for (int c = 0; c < 4; c++)
    kaddr[c] = q5 * 128 + ((32 * c + 16 * hi2) ^ swz);
#pragma unroll
  for (int m = 0; m < 8; m++)
    vaddr[m] = q5 * 128 + ((16 * m) ^ swz) + 8 * hi2;

  const int b_ = bh >> 4, h_ = bh & 15;
  const char* KsB = (const char*)&Ks[0][0];
  const char* VsB = (const char*)&Vs[0][0];

  const int wqbase = qt * 256 + w * 32;
  const int qrow = wqbase + q5;
  bf16x8 qf[4];
#pragma unroll
  for (int c = 0; c < 4; c++) {
    bf16x8 rq = *(const bf16x8*)&qb[(size_t)qrow * 64 + 16 * c + 8 * hi2];
    bf16x8 s_;
#pragma unroll
    for (int j2 = 0; j2 < 8; j2++)
      s_[j2] = (bf16)((float)rq[j2] * 0.18033688011112042f);
    qf[c] = s_;
  }

  f32x16 acc[2] = {};
  float l_r = 0.f;
  const int nkv = 4 * qt + 4;
  const int qmaxw = wqbase + 31;

  int cur = 0, nxt = 1, ovr = 2;
  stage(0, 0);
  stage(1, 1);
#pragma unroll 1
  for (int nt = 0; nt < nkv; ++nt) {
    if (nt + 2 < nkv) {
      stage(nt + 2, ovr);
      asm volatile("s_waitcnt vmcnt(4)" ::: "memory");
    } else if (nt + 1 < nkv) {
      asm volatile("s_waitcnt vmcnt(2)" ::: "memory");
    } else {
      asm volatile("s_waitcnt vmcnt(0)" ::: "memory");
    }
    __builtin_amdgcn_s_barrier();
    __builtin_amdgcn_sched_barrier(0);

    const bool live = (64 * nt) <= qmaxw;
    if (live) {
      const int bo = cur * 8192;
      float rs = 0.f;
#pragma unroll
      for (int T = 0; T < 2; T++) {
        f32x16 sc = {};
        __builtin_amdgcn_s_setprio(1);
#pragma unroll
        for (int c = 0; c < 4; c++) {
          bf16x8 kf = *(const bf16x8*)(KsB + bo + T * 4096 + kaddr[c]);
          sc = __builtin_amdgcn_mfma_f32_32x32x16_bf16(kf, qf[c], sc, 0, 0, 0);
        }
        __builtin_amdgcn_s_setprio(0);

        if (64 * nt + 32 * T + 31 > wqbase) {
#pragma unroll
          for (int r = 0; r < 16; r++) {
            int kvg = 64 * nt + 32 * T + (r & 3) + 8 * (r >> 2) + 4 * hi2;
            if (kvg > qrow) sc[r] = -1e30f;
          }
        }

        bf16x8 pa0, pa1;
#pragma unroll
        for (int r = 0; r < 8; r++) {
          float p0 = __builtin_amdgcn_exp2f(sc[r]);
          float p1 = __builtin_amdgcn_exp2f(sc[8 + r]);
          rs += p0 + p1;
          pa0[r] = (bf16)p0;
          pa1[r] = (bf16)p1;
        }

        __builtin_amdgcn_s_setprio(1);
#pragma unroll
        for (int dt = 0; dt < 2; dt++) {
          bf16x4 v0 = *(const bf16x4*)(VsB + bo + dt * 4096 + vaddr[4 * T]);
          bf16x4 v1 = *(const bf16x4*)(VsB + bo + dt * 4096 + vaddr[4 * T + 1]);
          bf16x8 bv;
#pragma unroll
          for (int j2 = 0; j2 < 4; j2++) { bv[j2] = v0[j2]; bv[4 + j2] = v1[j2]; }
          acc[dt] = __builtin_amdgcn_mfma_f32_32x32x16_bf16(pa0, bv, acc[dt], 0, 0, 0);
          v0 = *(const bf16x4*)(VsB + bo + dt * 4096 + vaddr[4 * T + 2]);
          v1 = *(const bf16x4*)(VsB + bo + dt * 4096 + vaddr[4 * T + 3]);
#pragma unroll
          for (int j2 = 0; j2 < 4; j2++) { bv[j2] = v0[j2]; bv[4 + j2] = v1[j2]; }
          acc[dt] = __builtin_amdgcn_mfma_f32_32x32x16_bf16(pa1, bv, acc[dt], 0, 0, 0);
        }
        __builtin_amdgcn_s_setprio(0);
      }
      rs += __shfl_xor(rs, 32);
      l_r += rs;
    }

    asm volatile("s_waitcnt lgkmcnt(0)" ::: "memory");
    __builtin_amdgcn_sched_barrier(0);
    __builtin_amdgcn_s_barrier();
    int t3 = cur; cur = nxt; nxt = ovr; ovr = t3;
  }

  float linv = 1.f / l_r;
#pragma unroll
  for (int r = 0; r < 16; r++) {
    int rmap = (r & 3) + 8 * (r >> 2) + 4 * hi2;
    float li = __shfl(linv, rmap);
    int rowq = wqbase + rmap;
    size_t rb = ((size_t)(b_ * S + rowq) << 10) + h_ * 64 + q5;
#pragma unroll
    for (int dt = 0; dt < 2; dt++)
      att[rb + 32 * dt] = (bf16)(acc[dt][r] * li);
  }
}

extern "C" void kernel_launch(void* const* d_in, const int* in_sizes, int n_in,
                              void* d_out, int out_size, void* d_ws, size_t ws_size,
                              hipStream_t stream) {
  const float* x  = (const float*)d_in[0];
  const int* tp   = (const int*)d_in[1];
  const float* wq = (const float*)d_in[2];
  const float* wk = (const float*)d_in[3];
  const float* wv = (const float*)d_in[4];
  const float* wo = (const float*)d_in[5];
  float* out = (float*)d_out;

  char* ws = (char*)d_ws;
  const size_t TEN = 16777216;  // 8192*1024*2 bytes
  bf16* x_bf    = (bf16*)(ws);
  bf16* q_bf    = (bf16*)(ws + TEN);
  bf16* k_bf    = (bf16*)(ws + 2 * TEN);
  bf16* v_bf    = (bf16*)(ws + 3 * TEN);
  bf16* wqkv_bf = (bf16*)(ws + 4 * TEN);          // 3072x1024 = 6MB
  bf16* wo_bf   = wqkv_bf + 3 * 1048576;          // 2MB
  bf16* tabc    = wo_bf + 1048576;                // 512KB
  bf16* tabs    = tabc + 262144;                  // 512KB
  bf16* att_bf  = x_bf;   // alias: x_bf dead after QKV projection

  cvt_all<<<7168, 256, 0, stream>>>(x, wq, wk, wv, wo, tp, x_bf, wqkv_bf,
                                    wo_bf, tabc, tabs);

  dim3 gq(32, 12);
  gemm8p<<<gq, 512, 0, stream>>>(x_bf, wqkv_bf, tabc, tabs, q_bf, k_bf, v_bf);

  attn_k<<<512, 512, 0, stream>>>(q_bf, k_bf, v_bf, att_bf);

  dim3 go(64, 8);
  gemm_wo<<<go, 256, 0, stream>>>(att_bf, wo_bf, out);
}

// Round 12
// 148.521 us; speedup vs baseline: 1.1696x; 1.0900x over previous
//
#include <hip/hip_runtime.h>
#include <hip/hip_bf16.h>
#include <stdint.h>

typedef __bf16 bf16;
typedef __bf16 bf16x4 __attribute__((ext_vector_type(4)));
typedef __bf16 bf16x8 __attribute__((ext_vector_type(8)));
typedef float f32x4 __attribute__((ext_vector_type(4)));
typedef float f32x16 __attribute__((ext_vector_type(16)));

#define GLDS16(g, l) __builtin_amdgcn_global_load_lds( \
    (const __attribute__((address_space(1))) void*)(g), \
    (__attribute__((address_space(3))) void*)(l), 16, 0, 0)

static constexpr int S = 2048;

// ---- fused f32->bf16 convert (x + 4 weights) + RoPE cos/sin table build ----
__global__ __launch_bounds__(256) void cvt_all(const float* __restrict__ x,
                                               const float* __restrict__ wq,
                                               const float* __restrict__ wk,
                                               const float* __restrict__ wv,
                                               const float* __restrict__ wo,
                                               const int* __restrict__ tp,
                                               bf16* __restrict__ xb,
                                               bf16* __restrict__ wqkvb,
                                               bf16* __restrict__ wob,
                                               bf16* __restrict__ tabc,
                                               bf16* __restrict__ tabs) {
  const int bid = blockIdx.x;
  if (bid >= 6144) {   // RoPE table: 8192 rows x 32 pairs
    int idx = (bid - 6144) * 256 + threadIdx.x;   // 0..262143
    int row = idx >> 5, pp = idx & 31;
    float p = (float)tp[row];
    float ang = p * exp2f((float)pp * -0.4152410118609203f);
    float sn, cs;
    sincosf(ang, &sn, &cs);
    tabc[idx] = (bf16)cs;
    tabs[idx] = (bf16)sn;
    return;
  }
  const float* src;
  bf16* dst;
  int i;
  if (bid < 4096) {            // x: 1,048,576 groups of 8
    src = x; dst = xb; i = bid * 256 + threadIdx.x;
  } else {                     // weights: 131,072 groups each
    int w = (bid - 4096) >> 9;
    i = ((bid - 4096) & 511) * 256 + threadIdx.x;
    src = (w == 0) ? wq : (w == 1) ? wk : (w == 2) ? wv : wo;
    dst = (w == 3) ? wob : wqkvb + (size_t)w * 1048576;
  }
  const float4* p = (const float4*)src + (size_t)i * 2;
  float4 a = p[0], b = p[1];
  bf16x8 o;
  o[0] = (bf16)a.x; o[1] = (bf16)a.y; o[2] = (bf16)a.z; o[3] = (bf16)a.w;
  o[4] = (bf16)b.x; o[5] = (bf16)b.y; o[6] = (bf16)b.z; o[7] = (bf16)b.w;
  *((bf16x8*)dst + i) = o;
}

// ---------------- NT GEMM, 128x128 tile, BK=32, 3 blocks/CU (r9-proven) -----
// 3-buffer LDS ring (48 KB) + counted vmcnt(8); chunk^((row>>1)&3) swizzle
// pre-applied to the global source (2-way-max bank aliasing on ds_read_b128).
// 2D grid natural dispatch: XCD = bm%8 -> blocks sharing x[bm] co-locate.
// MODE 0 (QKV, grid 64x24): bn<8 q, bn<16 k (table-RoPE, LDS-bounce coalesced
//   stores); bn>=16 v computed as W.x^T -> [b,h,dd,s] with coalesced rows.
// MODE 2 (wo, grid 64x8): f32 direct stores to [m][1024].
template <int MODE>
__global__ __launch_bounds__(256, 3) void gemm_k(const bf16* __restrict__ xA,
                                                 const bf16* __restrict__ wB,
                                                 const bf16* __restrict__ tabc,
                                                 const bf16* __restrict__ tabs,
                                                 bf16* __restrict__ oq,
                                                 bf16* __restrict__ ok,
                                                 bf16* __restrict__ ov,
                                                 float* __restrict__ outf) {
  constexpr int K = 1024;
  __shared__ __align__(16) char lds[49152];
  const int t = threadIdx.x, l = t & 63, wid = t >> 6;
  const int wm = wid >> 1, wn = wid & 1;
  const int bm = blockIdx.x, bn = blockIdx.y;

  // ---- block decode
  int sel, tA, tB;
  const bf16 *Ap, *Bp;
  if (MODE == 0) {
    if (bn < 16) {
      sel = bn >> 3;                                 // 0=q, 1=k
      tA = bm;                                       // s-tile 0..63
      tB = bn & 7;                                   // col-tile 0..7
      Ap = xA + (size_t)tA * 128 * K;
      Bp = wB + (size_t)(sel * 1024 + tB * 128) * K;
    } else {
      sel = 2;
      tA = bn - 16;                                  // dd-tile 0..7
      tB = bm;                                       // s-tile 0..63
      Ap = wB + (size_t)(2048 + tA * 128) * K;       // A = wv rows (dd)
      Bp = xA + (size_t)tB * 128 * K;                // B = x rows (s)
    }
  } else {
    sel = 3;
    tA = bm; tB = bn;
    Ap = xA + (size_t)tA * 128 * K;
    Bp = wB + (size_t)tB * 128 * K;
  }

  // ---- staging: 4 GLDS16/wave/step; lane l -> row l>>2, chunk l&3 (16B)
  const int lrow = l >> 2;
  const int csrc = ((l & 3) ^ ((l >> 3) & 3)) * 8;
  const bf16* aS = Ap + (size_t)(wid * 32 + lrow) * K + csrc;
  const bf16* bS = Bp + (size_t)(wid * 32 + lrow) * K + csrc;

  auto stage = [&](int kt, char* base) {
    GLDS16(aS + kt, base + (wid * 32) * 64);
    GLDS16(aS + (size_t)16 * K + kt, base + (wid * 32 + 16) * 64);
    GLDS16(bS + kt, base + 8192 + (wid * 32) * 64);
    GLDS16(bS + (size_t)16 * K + kt, base + 8192 + (wid * 32 + 16) * 64);
  };

  // ---- loop-invariant LDS read offsets
  int offA[4], offB[4];
#pragma unroll
  for (int f = 0; f < 4; f++) {
    int ra = wm * 64 + f * 16 + (l & 15);
    offA[f] = ra * 64 + (((l >> 4) ^ ((ra >> 1) & 3)) * 16);
    int rb = wn * 64 + f * 16 + (l & 15);
    offB[f] = 8192 + rb * 64 + (((l >> 4) ^ ((rb >> 1) & 3)) * 16);
  }

  f32x4 acc[4][4] = {};

  char* cur = lds;
  char* nxt = lds + 16384;
  char* ovr = lds + 32768;
  stage(0, cur);
  stage(32, nxt);
#pragma unroll 1
  for (int t_ = 0; t_ < 32; ++t_) {
    if (t_ + 2 < 32) {
      stage((t_ + 2) * 32, ovr);
      asm volatile("s_waitcnt vmcnt(8)" ::: "memory");
    } else if (t_ + 1 < 32) {
      asm volatile("s_waitcnt vmcnt(4)" ::: "memory");
    } else {
      asm volatile("s_waitcnt vmcnt(0)" ::: "memory");
    }
    __builtin_amdgcn_s_barrier();
    __builtin_amdgcn_sched_barrier(0);

    bf16x8 af[4], bg[4];
#pragma unroll
    for (int f = 0; f < 4; f++) {
      af[f] = *(const bf16x8*)(cur + offA[f]);
      bg[f] = *(const bf16x8*)(cur + offB[f]);
    }
    __builtin_amdgcn_s_setprio(1);
#pragma unroll
    for (int mi = 0; mi < 4; mi++)
#pragma unroll
      for (int ni = 0; ni < 4; ni++)
        acc[mi][ni] = __builtin_amdgcn_mfma_f32_16x16x32_bf16(
            af[mi], bg[ni], acc[mi][ni], 0, 0, 0);
    __builtin_amdgcn_s_setprio(0);
    asm volatile("s_waitcnt lgkmcnt(0)" ::: "memory");
    __builtin_amdgcn_sched_barrier(0);
    __builtin_amdgcn_s_barrier();
    char* tmp = cur; cur = nxt; nxt = ovr; ovr = tmp;
  }

  if (MODE == 2) {   // wo: direct f32 stores (64 B segments, full lines)
    const int rbase = tA * 128 + wm * 64 + (l >> 4) * 4;
    const int cbase = tB * 128 + wn * 64 + (l & 15);
#pragma unroll
    for (int mi = 0; mi < 4; mi++)
#pragma unroll
      for (int ni = 0; ni < 4; ni++)
#pragma unroll
        for (int r = 0; r < 4; r++)
          outf[(size_t)(rbase + mi * 16 + r) * 1024 + cbase + ni * 16] =
              acc[mi][ni][r];
    return;
  }

  // ---- E1: acc -> LDS [128][136] bf16 overlay (ring is dead)
#pragma unroll
  for (int mi = 0; mi < 4; mi++)
#pragma unroll
    for (int ni = 0; ni < 4; ni++)
#pragma unroll
      for (int r = 0; r < 4; r++) {
        int row = wm * 64 + mi * 16 + (l >> 4) * 4 + r;
        int col = wn * 64 + ni * 16 + (l & 15);
        *(bf16*)(lds + row * 272 + col * 2) = (bf16)acc[mi][ni][r];
      }
  __syncthreads();

  // ---- E2: coalesced stores; 16 lanes cover one row; RoPE via bf16 tables
#pragma unroll 2
  for (int i = 0; i < 8; ++i) {
    const int id = t + 256 * i;
    const int row = id >> 4, ch = id & 15;
    bf16x8 v8 = *(const bf16x8*)(lds + row * 272 + ch * 16);
    if (sel < 2) {
      const int m = tA * 128 + row;
      const int g = ch & 7;
      bf16x4 tc = *(const bf16x4*)(tabc + m * 32 + g * 4);
      bf16x4 tsn = *(const bf16x4*)(tabs + m * 32 + g * 4);
      bf16x8 o;
#pragma unroll
      for (int j = 0; j < 4; j++) {
        float cs = (float)tc[j], sn = (float)tsn[j];
        float e = (float)v8[2 * j], od = (float)v8[2 * j + 1];
        o[2 * j]     = (bf16)(e * cs - od * sn);
        o[2 * j + 1] = (bf16)(e * sn + od * cs);
      }
      bf16* dst = (sel == 0) ? oq : ok;
      const int h = tB * 2 + (ch >> 3);
      size_t idx = ((size_t)((m >> 11) * 16 + h) << 17) +
                   ((size_t)(m & 2047) << 6) + g * 8;
      *(bf16x8*)(dst + idx) = o;
    } else {
      const int dd = tA * 128 + row;
      const int h = dd >> 6;
      const int s0 = tB * 128 + ch * 8;
      size_t idx = ((size_t)((s0 >> 11) * 16 + h) << 17) +
                   ((size_t)(dd & 63) << 11) + (s0 & 2047);
      *(bf16x8*)(ov + idx) = v8;
    }
  }
}

// ---------------- causal flash attention, KVBLK=128 per barrier-pair --------
// 512 blocks (one (bh,qt) each), 8 waves, QBLK=256. Each step stages TWO
// 64-kv sub-tiles as side-by-side [64][64] blocks (inner addressing identical
// to the proven per-64 body; +8192 B per sub) -> barriers per kv halved.
// Double-buffered (64 KB), counted vmcnt(4) (next step's 4 loads in flight),
// 2 blocks/CU (VGPR capped by launch_bounds(512,4)). Swapped QK^T;
// sigma-permuted in-register P; no max-subtract softmax.
__global__ __launch_bounds__(512, 4) void attn_k(const bf16* __restrict__ q,
                                                 const bf16* __restrict__ k,
                                                 const bf16* __restrict__ vt,
                                                 bf16* __restrict__ att) {
  __shared__ bf16 Ks[2][8192];   // [buf][sub*4096 + kv64 x d64], swizzled
  __shared__ bf16 Vs[2][8192];   // [buf][sub*4096 + d64 x kv64], swizzled

  const int t = threadIdx.x, l = t & 63, w = t >> 6;   // w = 0..7
  const int hi2 = l >> 5, q5 = l & 31;

  const int raw = blockIdx.x;
  const int r2 = raw & 255;
  const int wg = (r2 & 7) * 32 + (r2 >> 3);      // 4 bh per XCD, L2-local
  const int bh = ((raw < 256) ? 0 : 32) + (wg >> 3);
  const int qt = (raw < 256) ? (wg & 7) : 7 - (wg & 7);

  const bf16* qb = q + (size_t)bh * S * 64;
  const bf16* kb = k + (size_t)bh * S * 64;
  const bf16* vb = vt + (size_t)bh * 64 * S;

  const int lrow = l >> 3;
  const int clog = ((l & 7) ^ (lrow & 7)) * 8;   // pre-swizzled source chunk

  auto stage = [&](int st, int b) {
#pragma unroll
    for (int sub = 0; sub < 2; sub++) {
      const int nt = 2 * st + sub;
      GLDS16(kb + (size_t)(nt * 64 + w * 8 + lrow) * 64 + clog,
             &Ks[b][sub * 4096 + w * 512]);
      GLDS16(vb + (size_t)(w * 8 + lrow) * S + nt * 64 + clog,
             &Vs[b][sub * 4096 + w * 512]);
    }
  };

  const int swz = (q5 & 7) << 4;
  int kaddr[4], vaddr[8];
#pragma unroll
  for (int c = 0; c < 4; c++)
    kaddr[c] = q5 * 128 + ((32 * c + 16 * hi2) ^ swz);
#pragma unroll
  for (int m = 0; m < 8; m++)
    vaddr[m] = q5 * 128 + ((16 * m) ^ swz) + 8 * hi2;

  const int b_ = bh >> 4, h_ = bh & 15;
  const char* KsB = (const char*)&Ks[0][0];
  const char* VsB = (const char*)&Vs[0][0];

  const int wqbase = qt * 256 + w * 32;
  const int qrow = wqbase + q5;
  bf16x8 qf[4];   // Q^T B-operand, chunk c: d = 16c+8*hi2+(0..7); scaled
#pragma unroll
  for (int c = 0; c < 4; c++) {
    bf16x8 rq = *(const bf16x8*)&qb[(size_t)qrow * 64 + 16 * c + 8 * hi2];
    bf16x8 s_;
#pragma unroll
    for (int j2 = 0; j2 < 8; j2++)
      s_[j2] = (bf16)((float)rq[j2] * 0.18033688011112042f);
    qf[c] = s_;
  }

  f32x16 acc[2] = {};
  float l_r = 0.f;
  const int nst = 2 * qt + 2;            // steps of 128 kv
  const int qmaxw = wqbase + 31;

  stage(0, 0);
#pragma unroll 1
  for (int s = 0; s < nst; ++s) {
    if (s + 1 < nst) {
      stage(s + 1, (s + 1) & 1);
      asm volatile("s_waitcnt vmcnt(4)" ::: "memory");
    } else {
      asm volatile("s_waitcnt vmcnt(0)" ::: "memory");
    }
    __builtin_amdgcn_s_barrier();
    __builtin_amdgcn_sched_barrier(0);

    const int bo_buf = (s & 1) * 16384;
    float rs = 0.f;
#pragma unroll
    for (int sub = 0; sub < 2; sub++) {
      const int nt = 2 * s + sub;
      if (64 * nt > qmaxw) continue;     // wave-uniform causal gate
      const int bo = bo_buf + sub * 8192;
#pragma unroll
      for (int T = 0; T < 2; T++) {
        // S^T = K Q^T for half-tile T (kv 32T..32T+31 within sub)
        f32x16 sc = {};
        __builtin_amdgcn_s_setprio(1);
#pragma unroll
        for (int c = 0; c < 4; c++) {
          bf16x8 kf = *(const bf16x8*)(KsB + bo + T * 4096 + kaddr[c]);
          sc = __builtin_amdgcn_mfma_f32_32x32x16_bf16(kf, qf[c], sc, 0, 0, 0);
        }
        __builtin_amdgcn_s_setprio(0);

        if (64 * nt + 32 * T + 31 > wqbase) {   // causal mask
#pragma unroll
          for (int r = 0; r < 16; r++) {
            int kvg = 64 * nt + 32 * T + (r & 3) + 8 * (r >> 2) + 4 * hi2;
            if (kvg > qrow) sc[r] = -1e30f;
          }
        }

        // softmax (no max-subtract) + pack P for this half
        bf16x8 pa0, pa1;
#pragma unroll
        for (int r = 0; r < 8; r++) {
          float p0 = __builtin_amdgcn_exp2f(sc[r]);
          float p1 = __builtin_amdgcn_exp2f(sc[8 + r]);
          rs += p0 + p1;
          pa0[r] = (bf16)p0;
          pa1[r] = (bf16)p1;
        }

        // O += P'V for this half
        __builtin_amdgcn_s_setprio(1);
#pragma unroll
        for (int dt = 0; dt < 2; dt++) {
          bf16x4 v0 = *(const bf16x4*)(VsB + bo + dt * 4096 + vaddr[4 * T]);
          bf16x4 v1 = *(const bf16x4*)(VsB + bo + dt * 4096 + vaddr[4 * T + 1]);
          bf16x8 bv;
#pragma unroll
          for (int j2 = 0; j2 < 4; j2++) { bv[j2] = v0[j2]; bv[4 + j2] = v1[j2]; }
          acc[dt] = __builtin_amdgcn_mfma_f32_32x32x16_bf16(pa0, bv, acc[dt], 0, 0, 0);
          v0 = *(const bf16x4*)(VsB + bo + dt * 4096 + vaddr[4 * T + 2]);
          v1 = *(const bf16x4*)(VsB + bo + dt * 4096 + vaddr[4 * T + 3]);
#pragma unroll
          for (int j2 = 0; j2 < 4; j2++) { bv[j2] = v0[j2]; bv[4 + j2] = v1[j2]; }
          acc[dt] = __builtin_amdgcn_mfma_f32_32x32x16_bf16(pa1, bv, acc[dt], 0, 0, 0);
        }
        __builtin_amdgcn_s_setprio(0);
      }
    }
    rs += __shfl_xor(rs, 32);
    l_r += rs;

    asm volatile("s_waitcnt lgkmcnt(0)" ::: "memory");
    __builtin_amdgcn_sched_barrier(0);
    __builtin_amdgcn_s_barrier();
  }

  // epilogue: O row = qt*256 + w*32 + rmap(r,hi2), col d = 32dt + q5
  float linv = 1.f / l_r;
#pragma unroll
  for (int r = 0; r < 16; r++) {
    int rmap = (r & 3) + 8 * (r >> 2) + 4 * hi2;
    float li = __shfl(linv, rmap);
    int rowq = wqbase + rmap;
    size_t rb = ((size_t)(b_ * S + rowq) << 10) + h_ * 64 + q5;
#pragma unroll
    for (int dt = 0; dt < 2; dt++)
      att[rb + 32 * dt] = (bf16)(acc[dt][r] * li);
  }
}

extern "C" void kernel_launch(void* const* d_in, const int* in_sizes, int n_in,
                              void* d_out, int out_size, void* d_ws, size_t ws_size,
                              hipStream_t stream) {
  const float* x  = (const float*)d_in[0];
  const int* tp   = (const int*)d_in[1];
  const float* wq = (const float*)d_in[2];
  const float* wk = (const float*)d_in[3];
  const float* wv = (const float*)d_in[4];
  const float* wo = (const float*)d_in[5];
  float* out = (float*)d_out;

  char* ws = (char*)d_ws;
  const size_t TEN = 16777216;  // 8192*1024*2 bytes
  bf16* x_bf    = (bf16*)(ws);
  bf16* q_bf    = (bf16*)(ws + TEN);
  bf16* k_bf    = (bf16*)(ws + 2 * TEN);
  bf16* v_bf    = (bf16*)(ws + 3 * TEN);
  bf16* wqkv_bf = (bf16*)(ws + 4 * TEN);          // 3072x1024 = 6MB
  bf16* wo_bf   = wqkv_bf + 3 * 1048576;          // 2MB
  bf16* tabc    = wo_bf + 1048576;                // 512KB (8192x32 bf16)
  bf16* tabs    = tabc + 262144;                  // 512KB
  bf16* att_bf  = x_bf;   // alias: x_bf dead after QKV projection

  cvt_all<<<7168, 256, 0, stream>>>(x, wq, wk, wv, wo, tp, x_bf, wqkv_bf,
                                    wo_bf, tabc, tabs);

  dim3 gq(64, 24);
  gemm_k<0><<<gq, 256, 0, stream>>>(x_bf, wqkv_bf, tabc, tabs, q_bf, k_bf,
                                    v_bf, nullptr);

  attn_k<<<512, 512, 0, stream>>>(q_bf, k_bf, v_bf, att_bf);

  dim3 go(64, 8);
  gemm_k<2><<<go, 256, 0, stream>>>(att_bf, wo_bf, nullptr, nullptr, nullptr,
                                    nullptr, nullptr, out);
}

// Round 13
// 148.000 us; speedup vs baseline: 1.1737x; 1.0035x over previous
//
#include <hip/hip_runtime.h>
#include <hip/hip_bf16.h>
#include <stdint.h>

typedef __bf16 bf16;
typedef __bf16 bf16x4 __attribute__((ext_vector_type(4)));
typedef __bf16 bf16x8 __attribute__((ext_vector_type(8)));
typedef float f32x4 __attribute__((ext_vector_type(4)));
typedef float f32x16 __attribute__((ext_vector_type(16)));

#define GLDS16(g, l) __builtin_amdgcn_global_load_lds( \
    (const __attribute__((address_space(1))) void*)(g), \
    (__attribute__((address_space(3))) void*)(l), 16, 0, 0)

static constexpr int S = 2048;

// ---- fused f32->bf16 convert (x + 4 weights) + RoPE cos/sin table build ----
__global__ __launch_bounds__(256) void cvt_all(const float* __restrict__ x,
                                               const float* __restrict__ wq,
                                               const float* __restrict__ wk,
                                               const float* __restrict__ wv,
                                               const float* __restrict__ wo,
                                               const int* __restrict__ tp,
                                               bf16* __restrict__ xb,
                                               bf16* __restrict__ wqkvb,
                                               bf16* __restrict__ wob,
                                               bf16* __restrict__ tabc,
                                               bf16* __restrict__ tabs) {
  const int bid = blockIdx.x;
  if (bid >= 6144) {   // RoPE table: 8192 rows x 32 pairs
    int idx = (bid - 6144) * 256 + threadIdx.x;   // 0..262143
    int row = idx >> 5, pp = idx & 31;
    float p = (float)tp[row];
    float ang = p * exp2f((float)pp * -0.4152410118609203f);
    float sn, cs;
    sincosf(ang, &sn, &cs);
    tabc[idx] = (bf16)cs;
    tabs[idx] = (bf16)sn;
    return;
  }
  const float* src;
  bf16* dst;
  int i;
  if (bid < 4096) {            // x: 1,048,576 groups of 8
    src = x; dst = xb; i = bid * 256 + threadIdx.x;
  } else {                     // weights: 131,072 groups each
    int w = (bid - 4096) >> 9;
    i = ((bid - 4096) & 511) * 256 + threadIdx.x;
    src = (w == 0) ? wq : (w == 1) ? wk : (w == 2) ? wv : wo;
    dst = (w == 3) ? wob : wqkvb + (size_t)w * 1048576;
  }
  const float4* p = (const float4*)src + (size_t)i * 2;
  float4 a = p[0], b = p[1];
  bf16x8 o;
  o[0] = (bf16)a.x; o[1] = (bf16)a.y; o[2] = (bf16)a.z; o[3] = (bf16)a.w;
  o[4] = (bf16)b.x; o[5] = (bf16)b.y; o[6] = (bf16)b.z; o[7] = (bf16)b.w;
  *((bf16x8*)dst + i) = o;
}

// ---------------- NT GEMM, 128x128 tile, BK=32, dbuf, 4+ blocks/CU ----------
// Double-buffered LDS ring (32 KB) + counted vmcnt(4): 1-step prefetch slack
// (~2600 cyc >> 900 cyc HBM latency) traded for occupancy — LDS 48->32 KB
// lifts residency 3 -> 4-5 blocks/CU (16-20 waves) to fill barrier bubbles.
// chunk^((row>>1)&3) swizzle pre-applied to the global source (2-way-max
// bank aliasing). 2D grid natural dispatch: XCD = bm%8 -> L2 co-location.
// MODE 0 (QKV, grid 64x24): bn<8 q, bn<16 k (table-RoPE, LDS-bounce stores,
//   2-pass half-tile overlay reusing the dead ring); bn>=16 v = W.x^T ->
//   [b,h,dd,s] coalesced rows.
// MODE 2 (wo, grid 64x8): f32 direct stores to [m][1024].
template <int MODE>
__global__ __launch_bounds__(256, 4) void gemm_k(const bf16* __restrict__ xA,
                                                 const bf16* __restrict__ wB,
                                                 const bf16* __restrict__ tabc,
                                                 const bf16* __restrict__ tabs,
                                                 bf16* __restrict__ oq,
                                                 bf16* __restrict__ ok,
                                                 bf16* __restrict__ ov,
                                                 float* __restrict__ outf) {
  constexpr int K = 1024;
  __shared__ __align__(16) char lds[32768];
  const int t = threadIdx.x, l = t & 63, wid = t >> 6;
  const int wm = wid >> 1, wn = wid & 1;
  const int bm = blockIdx.x, bn = blockIdx.y;

  // ---- block decode
  int sel, tA, tB;
  const bf16 *Ap, *Bp;
  if (MODE == 0) {
    if (bn < 16) {
      sel = bn >> 3;                                 // 0=q, 1=k
      tA = bm;                                       // s-tile 0..63
      tB = bn & 7;                                   // col-tile 0..7
      Ap = xA + (size_t)tA * 128 * K;
      Bp = wB + (size_t)(sel * 1024 + tB * 128) * K;
    } else {
      sel = 2;
      tA = bn - 16;                                  // dd-tile 0..7
      tB = bm;                                       // s-tile 0..63
      Ap = wB + (size_t)(2048 + tA * 128) * K;       // A = wv rows (dd)
      Bp = xA + (size_t)tB * 128 * K;                // B = x rows (s)
    }
  } else {
    sel = 3;
    tA = bm; tB = bn;
    Ap = xA + (size_t)tA * 128 * K;
    Bp = wB + (size_t)tB * 128 * K;
  }

  // ---- staging: 4 GLDS16/wave/step; lane l -> row l>>2, chunk l&3 (16B)
  const int lrow = l >> 2;
  const int csrc = ((l & 3) ^ ((l >> 3) & 3)) * 8;
  const bf16* aS = Ap + (size_t)(wid * 32 + lrow) * K + csrc;
  const bf16* bS = Bp + (size_t)(wid * 32 + lrow) * K + csrc;

  auto stage = [&](int kt, char* base) {
    GLDS16(aS + kt, base + (wid * 32) * 64);
    GLDS16(aS + (size_t)16 * K + kt, base + (wid * 32 + 16) * 64);
    GLDS16(bS + kt, base + 8192 + (wid * 32) * 64);
    GLDS16(bS + (size_t)16 * K + kt, base + 8192 + (wid * 32 + 16) * 64);
  };

  // ---- loop-invariant LDS read offsets
  int offA[4], offB[4];
#pragma unroll
  for (int f = 0; f < 4; f++) {
    int ra = wm * 64 + f * 16 + (l & 15);
    offA[f] = ra * 64 + (((l >> 4) ^ ((ra >> 1) & 3)) * 16);
    int rb = wn * 64 + f * 16 + (l & 15);
    offB[f] = 8192 + rb * 64 + (((l >> 4) ^ ((rb >> 1) & 3)) * 16);
  }

  f32x4 acc[4][4] = {};

  stage(0, lds);
#pragma unroll 1
  for (int t_ = 0; t_ < 32; ++t_) {
    if (t_ + 1 < 32) {
      stage((t_ + 1) * 32, lds + ((t_ + 1) & 1) * 16384);
      asm volatile("s_waitcnt vmcnt(4)" ::: "memory");
    } else {
      asm volatile("s_waitcnt vmcnt(0)" ::: "memory");
    }
    __builtin_amdgcn_s_barrier();
    __builtin_amdgcn_sched_barrier(0);

    const char* cur = lds + (t_ & 1) * 16384;
    bf16x8 af[4], bg[4];
#pragma unroll
    for (int f = 0; f < 4; f++) {
      af[f] = *(const bf16x8*)(cur + offA[f]);
      bg[f] = *(const bf16x8*)(cur + offB[f]);
    }
    __builtin_amdgcn_s_setprio(1);
#pragma unroll
    for (int mi = 0; mi < 4; mi++)
#pragma unroll
      for (int ni = 0; ni < 4; ni++)
        acc[mi][ni] = __builtin_amdgcn_mfma_f32_16x16x32_bf16(
            af[mi], bg[ni], acc[mi][ni], 0, 0, 0);
    __builtin_amdgcn_s_setprio(0);
    asm volatile("s_waitcnt lgkmcnt(0)" ::: "memory");
    __builtin_amdgcn_sched_barrier(0);
    __builtin_amdgcn_s_barrier();
  }

  if (MODE == 2) {   // wo: direct f32 stores (64 B segments, full lines)
    const int rbase = tA * 128 + wm * 64 + (l >> 4) * 4;
    const int cbase = tB * 128 + wn * 64 + (l & 15);
#pragma unroll
    for (int mi = 0; mi < 4; mi++)
#pragma unroll
      for (int ni = 0; ni < 4; ni++)
#pragma unroll
        for (int r = 0; r < 4; r++)
          outf[(size_t)(rbase + mi * 16 + r) * 1024 + cbase + ni * 16] =
              acc[mi][ni][r];
    return;
  }

  // ---- 2-pass half-tile epilogue via 64x272B overlay (reuses dead ring)
  __syncthreads();
#pragma unroll 1
  for (int pass = 0; pass < 2; ++pass) {
    if (wm == pass) {   // waves owning rows [pass*64, pass*64+64)
#pragma unroll
      for (int mi = 0; mi < 4; mi++)
#pragma unroll
        for (int ni = 0; ni < 4; ni++)
#pragma unroll
          for (int r = 0; r < 4; r++) {
            int rloc = mi * 16 + (l >> 4) * 4 + r;       // 0..63
            int col = wn * 64 + ni * 16 + (l & 15);      // 0..127
            *(bf16*)(lds + rloc * 272 + col * 2) = (bf16)acc[mi][ni][r];
          }
    }
    __syncthreads();
#pragma unroll 2
    for (int i = 0; i < 4; ++i) {
      const int id = t + 256 * i;
      const int rloc = id >> 4, ch = id & 15;
      bf16x8 v8 = *(const bf16x8*)(lds + rloc * 272 + ch * 16);
      const int row = pass * 64 + rloc;
      if (sel < 2) {
        const int m = tA * 128 + row;
        const int g = ch & 7;
        bf16x4 tc = *(const bf16x4*)(tabc + m * 32 + g * 4);
        bf16x4 tsn = *(const bf16x4*)(tabs + m * 32 + g * 4);
        bf16x8 o;
#pragma unroll
        for (int j = 0; j < 4; j++) {
          float cs = (float)tc[j], sn = (float)tsn[j];
          float e = (float)v8[2 * j], od = (float)v8[2 * j + 1];
          o[2 * j]     = (bf16)(e * cs - od * sn);
          o[2 * j + 1] = (bf16)(e * sn + od * cs);
        }
        bf16* dst = (sel == 0) ? oq : ok;
        const int h = tB * 2 + (ch >> 3);
        size_t idx = ((size_t)((m >> 11) * 16 + h) << 17) +
                     ((size_t)(m & 2047) << 6) + g * 8;
        *(bf16x8*)(dst + idx) = o;
      } else {
        const int dd = tA * 128 + row;
        const int h = dd >> 6;
        const int s0 = tB * 128 + ch * 8;
        size_t idx = ((size_t)((s0 >> 11) * 16 + h) << 17) +
                     ((size_t)(dd & 63) << 11) + (s0 & 2047);
        *(bf16x8*)(ov + idx) = v8;
      }
    }
    __syncthreads();
  }
}

// ---------------- causal flash attention, KVBLK=128 per barrier-pair --------
// (r12-proven) 512 blocks (one (bh,qt) each), 8 waves, QBLK=256. Each step
// stages TWO 64-kv sub-tiles; barriers per kv halved. Double-buffered (64 KB),
// counted vmcnt(4), 2 blocks/CU. Swapped QK^T; sigma-permuted in-register P;
// no max-subtract softmax.
__global__ __launch_bounds__(512, 4) void attn_k(const bf16* __restrict__ q,
                                                 const bf16* __restrict__ k,
                                                 const bf16* __restrict__ vt,
                                                 bf16* __restrict__ att) {
  __shared__ bf16 Ks[2][8192];   // [buf][sub*4096 + kv64 x d64], swizzled
  __shared__ bf16 Vs[2][8192];   // [buf][sub*4096 + d64 x kv64], swizzled

  const int t = threadIdx.x, l = t & 63, w = t >> 6;   // w = 0..7
  const int hi2 = l >> 5, q5 = l & 31;

  const int raw = blockIdx.x;
  const int r2 = raw & 255;
  const int wg = (r2 & 7) * 32 + (r2 >> 3);      // 4 bh per XCD, L2-local
  const int bh = ((raw < 256) ? 0 : 32) + (wg >> 3);
  const int qt = (raw < 256) ? (wg & 7) : 7 - (wg & 7);

  const bf16* qb = q + (size_t)bh * S * 64;
  const bf16* kb = k + (size_t)bh * S * 64;
  const bf16* vb = vt + (size_t)bh * 64 * S;

  const int lrow = l >> 3;
  const int clog = ((l & 7) ^ (lrow & 7)) * 8;   // pre-swizzled source chunk

  auto stage = [&](int st, int b) {
#pragma unroll
    for (int sub = 0; sub < 2; sub++) {
      const int nt = 2 * st + sub;
      GLDS16(kb + (size_t)(nt * 64 + w * 8 + lrow) * 64 + clog,
             &Ks[b][sub * 4096 + w * 512]);
      GLDS16(vb + (size_t)(w * 8 + lrow) * S + nt * 64 + clog,
             &Vs[b][sub * 4096 + w * 512]);
    }
  };

  const int swz = (q5 & 7) << 4;
  int kaddr[4], vaddr[8];
#pragma unroll
  for (int c = 0; c < 4; c++)
    kaddr[c] = q5 * 128 + ((32 * c + 16 * hi2) ^ swz);
#pragma unroll
  for (int m = 0; m < 8; m++)
    vaddr[m] = q5 * 128 + ((16 * m) ^ swz) + 8 * hi2;

  const int b_ = bh >> 4, h_ = bh & 15;
  const char* KsB = (const char*)&Ks[0][0];
  const char* VsB = (const char*)&Vs[0][0];

  const int wqbase = qt * 256 + w * 32;
  const int qrow = wqbase + q5;
  bf16x8 qf[4];   // Q^T B-operand, chunk c: d = 16c+8*hi2+(0..7); scaled
#pragma unroll
  for (int c = 0; c < 4; c++) {
    bf16x8 rq = *(const bf16x8*)&qb[(size_t)qrow * 64 + 16 * c + 8 * hi2];
    bf16x8 s_;
#pragma unroll
    for (int j2 = 0; j2 < 8; j2++)
      s_[j2] = (bf16)((float)rq[j2] * 0.18033688011112042f);
    qf[c] = s_;
  }

  f32x16 acc[2] = {};
  float l_r = 0.f;
  const int nst = 2 * qt + 2;            // steps of 128 kv
  const int qmaxw = wqbase + 31;

  stage(0, 0);
#pragma unroll 1
  for (int s = 0; s < nst; ++s) {
    if (s + 1 < nst) {
      stage(s + 1, (s + 1) & 1);
      asm volatile("s_waitcnt vmcnt(4)" ::: "memory");
    } else {
      asm volatile("s_waitcnt vmcnt(0)" ::: "memory");
    }
    __builtin_amdgcn_s_barrier();
    __builtin_amdgcn_sched_barrier(0);

    const int bo_buf = (s & 1) * 16384;
    float rs = 0.f;
#pragma unroll
    for (int sub = 0; sub < 2; sub++) {
      const int nt = 2 * s + sub;
      if (64 * nt > qmaxw) continue;     // wave-uniform causal gate
      const int bo = bo_buf + sub * 8192;
#pragma unroll
      for (int T = 0; T < 2; T++) {
        // S^T = K Q^T for half-tile T (kv 32T..32T+31 within sub)
        f32x16 sc = {};
        __builtin_amdgcn_s_setprio(1);
#pragma unroll
        for (int c = 0; c < 4; c++) {
          bf16x8 kf = *(const bf16x8*)(KsB + bo + T * 4096 + kaddr[c]);
          sc = __builtin_amdgcn_mfma_f32_32x32x16_bf16(kf, qf[c], sc, 0, 0, 0);
        }
        __builtin_amdgcn_s_setprio(0);

        if (64 * nt + 32 * T + 31 > wqbase) {   // causal mask
#pragma unroll
          for (int r = 0; r < 16; r++) {
            int kvg = 64 * nt + 32 * T + (r & 3) + 8 * (r >> 2) + 4 * hi2;
            if (kvg > qrow) sc[r] = -1e30f;
          }
        }

        // softmax (no max-subtract) + pack P for this half
        bf16x8 pa0, pa1;
#pragma unroll
        for (int r = 0; r < 8; r++) {
          float p0 = __builtin_amdgcn_exp2f(sc[r]);
          float p1 = __builtin_amdgcn_exp2f(sc[8 + r]);
          rs += p0 + p1;
          pa0[r] = (bf16)p0;
          pa1[r] = (bf16)p1;
        }

        // O += P'V for this half
        __builtin_amdgcn_s_setprio(1);
#pragma unroll
        for (int dt = 0; dt < 2; dt++) {
          bf16x4 v0 = *(const bf16x4*)(VsB + bo + dt * 4096 + vaddr[4 * T]);
          bf16x4 v1 = *(const bf16x4*)(VsB + bo + dt * 4096 + vaddr[4 * T + 1]);
          bf16x8 bv;
#pragma unroll
          for (int j2 = 0; j2 < 4; j2++) { bv[j2] = v0[j2]; bv[4 + j2] = v1[j2]; }
          acc[dt] = __builtin_amdgcn_mfma_f32_32x32x16_bf16(pa0, bv, acc[dt], 0, 0, 0);
          v0 = *(const bf16x4*)(VsB + bo + dt * 4096 + vaddr[4 * T + 2]);
          v1 = *(const bf16x4*)(VsB + bo + dt * 4096 + vaddr[4 * T + 3]);
#pragma unroll
          for (int j2 = 0; j2 < 4; j2++) { bv[j2] = v0[j2]; bv[4 + j2] = v1[j2]; }
          acc[dt] = __builtin_amdgcn_mfma_f32_32x32x16_bf16(pa1, bv, acc[dt], 0, 0, 0);
        }
        __builtin_amdgcn_s_setprio(0);
      }
    }
    rs += __shfl_xor(rs, 32);
    l_r += rs;

    asm volatile("s_waitcnt lgkmcnt(0)" ::: "memory");
    __builtin_amdgcn_sched_barrier(0);
    __builtin_amdgcn_s_barrier();
  }

  // epilogue: O row = qt*256 + w*32 + rmap(r,hi2), col d = 32dt + q5
  float linv = 1.f / l_r;
#pragma unroll
  for (int r = 0; r < 16; r++) {
    int rmap = (r & 3) + 8 * (r >> 2) + 4 * hi2;
    float li = __shfl(linv, rmap);
    int rowq = wqbase + rmap;
    size_t rb = ((size_t)(b_ * S + rowq) << 10) + h_ * 64 + q5;
#pragma unroll
    for (int dt = 0; dt < 2; dt++)
      att[rb + 32 * dt] = (bf16)(acc[dt][r] * li);
  }
}

extern "C" void kernel_launch(void* const* d_in, const int* in_sizes, int n_in,
                              void* d_out, int out_size, void* d_ws, size_t ws_size,
                              hipStream_t stream) {
  const float* x  = (const float*)d_in[0];
  const int* tp   = (const int*)d_in[1];
  const float* wq = (const float*)d_in[2];
  const float* wk = (const float*)d_in[3];
  const float* wv = (const float*)d_in[4];
  const float* wo = (const float*)d_in[5];
  float* out = (float*)d_out;

  char* ws = (char*)d_ws;
  const size_t TEN = 16777216;  // 8192*1024*2 bytes
  bf16* x_bf    = (bf16*)(ws);
  bf16* q_bf    = (bf16*)(ws + TEN);
  bf16* k_bf    = (bf16*)(ws + 2 * TEN);
  bf16* v_bf    = (bf16*)(ws + 3 * TEN);
  bf16* wqkv_bf = (bf16*)(ws + 4 * TEN);          // 3072x1024 = 6MB
  bf16* wo_bf   = wqkv_bf + 3 * 1048576;          // 2MB
  bf16* tabc    = wo_bf + 1048576;                // 512KB (8192x32 bf16)
  bf16* tabs    = tabc + 262144;                  // 512KB
  bf16* att_bf  = x_bf;   // alias: x_bf dead after QKV projection

  cvt_all<<<7168, 256, 0, stream>>>(x, wq, wk, wv, wo, tp, x_bf, wqkv_bf,
                                    wo_bf, tabc, tabs);

  dim3 gq(64, 24);
  gemm_k<0><<<gq, 256, 0, stream>>>(x_bf, wqkv_bf, tabc, tabs, q_bf, k_bf,
                                    v_bf, nullptr);

  attn_k<<<512, 512, 0, stream>>>(q_bf, k_bf, v_bf, att_bf);

  dim3 go(64, 8);
  gemm_k<2><<<go, 256, 0, stream>>>(att_bf, wo_bf, nullptr, nullptr, nullptr,
                                    nullptr, nullptr, out);
}

// Round 15
// 147.937 us; speedup vs baseline: 1.1742x; 1.0004x over previous
//
#include <hip/hip_runtime.h>
#include <hip/hip_bf16.h>
#include <stdint.h>

typedef __bf16 bf16;
typedef __bf16 bf16x4 __attribute__((ext_vector_type(4)));
typedef __bf16 bf16x8 __attribute__((ext_vector_type(8)));
typedef float f32x4 __attribute__((ext_vector_type(4)));
typedef float f32x16 __attribute__((ext_vector_type(16)));

#define GLDS16(g, l) __builtin_amdgcn_global_load_lds( \
    (const __attribute__((address_space(1))) void*)(g), \
    (__attribute__((address_space(3))) void*)(l), 16, 0, 0)

static constexpr int S = 2048;

// ---- fused f32->bf16 convert (x + 4 weights) + RoPE cos/sin table build ----
__global__ __launch_bounds__(256) void cvt_all(const float* __restrict__ x,
                                               const float* __restrict__ wq,
                                               const float* __restrict__ wk,
                                               const float* __restrict__ wv,
                                               const float* __restrict__ wo,
                                               const int* __restrict__ tp,
                                               bf16* __restrict__ xb,
                                               bf16* __restrict__ wqkvb,
                                               bf16* __restrict__ wob,
                                               bf16* __restrict__ tabc,
                                               bf16* __restrict__ tabs) {
  const int bid = blockIdx.x;
  if (bid >= 6144) {   // RoPE table: 8192 rows x 32 pairs
    int idx = (bid - 6144) * 256 + threadIdx.x;   // 0..262143
    int row = idx >> 5, pp = idx & 31;
    float p = (float)tp[row];
    float ang = p * exp2f((float)pp * -0.4152410118609203f);
    float sn, cs;
    sincosf(ang, &sn, &cs);
    tabc[idx] = (bf16)cs;
    tabs[idx] = (bf16)sn;
    return;
  }
  const float* src;
  bf16* dst;
  int i;
  if (bid < 4096) {            // x: 1,048,576 groups of 8
    src = x; dst = xb; i = bid * 256 + threadIdx.x;
  } else {                     // weights: 131,072 groups each
    int w = (bid - 4096) >> 9;
    i = ((bid - 4096) & 511) * 256 + threadIdx.x;
    src = (w == 0) ? wq : (w == 1) ? wk : (w == 2) ? wv : wo;
    dst = (w == 3) ? wob : wqkvb + (size_t)w * 1048576;
  }
  const float4* p = (const float4*)src + (size_t)i * 2;
  float4 a = p[0], b = p[1];
  bf16x8 o;
  o[0] = (bf16)a.x; o[1] = (bf16)a.y; o[2] = (bf16)a.z; o[3] = (bf16)a.w;
  o[4] = (bf16)b.x; o[5] = (bf16)b.y; o[6] = (bf16)b.z; o[7] = (bf16)b.w;
  *((bf16x8*)dst + i) = o;
}

// ---------------- NT GEMM, 128x128 tile, BK=32, 3-ring, ONE barrier/step ----
// Corrected r14: stage is issued AFTER the entry barrier. Ordering proof:
// (1) WAR: ovr at step t == cur at step t-1. A wave passes barrier t only
//     after its step-(t-1) ds_reads completed (compiler lgkm waits precede
//     the MFMAs, which precede the barrier in program order). stage(ovr) is
//     issued after passing barrier t => after ALL waves' reads of ovr.
// (2) RAW: tile t staged at step t-2 (2 steps slack); vmcnt(4) before the
//     barrier leaves only tile t+1's 4 loads in flight.
// One rendezvous per step, no lgkm drain -> waves skew within a step.
// chunk^((row>>1)&3) swizzle pre-applied to the global source. 2D grid
// natural dispatch: XCD = bm%8 -> L2 co-location.
// MODE 0 (QKV, grid 64x24): bn<8 q, bn<16 k (table-RoPE, LDS-bounce stores);
//   bn>=16 v = W.x^T -> [b,h,dd,s] coalesced rows.
// MODE 2 (wo, grid 64x8): f32 direct stores to [m][1024].
template <int MODE>
__global__ __launch_bounds__(256, 3) void gemm_k(const bf16* __restrict__ xA,
                                                 const bf16* __restrict__ wB,
                                                 const bf16* __restrict__ tabc,
                                                 const bf16* __restrict__ tabs,
                                                 bf16* __restrict__ oq,
                                                 bf16* __restrict__ ok,
                                                 bf16* __restrict__ ov,
                                                 float* __restrict__ outf) {
  constexpr int K = 1024;
  __shared__ __align__(16) char lds[49152];
  const int t = threadIdx.x, l = t & 63, wid = t >> 6;
  const int wm = wid >> 1, wn = wid & 1;
  const int bm = blockIdx.x, bn = blockIdx.y;

  // ---- block decode
  int sel, tA, tB;
  const bf16 *Ap, *Bp;
  if (MODE == 0) {
    if (bn < 16) {
      sel = bn >> 3;                                 // 0=q, 1=k
      tA = bm;                                       // s-tile 0..63
      tB = bn & 7;                                   // col-tile 0..7
      Ap = xA + (size_t)tA * 128 * K;
      Bp = wB + (size_t)(sel * 1024 + tB * 128) * K;
    } else {
      sel = 2;
      tA = bn - 16;                                  // dd-tile 0..7
      tB = bm;                                       // s-tile 0..63
      Ap = wB + (size_t)(2048 + tA * 128) * K;       // A = wv rows (dd)
      Bp = xA + (size_t)tB * 128 * K;                // B = x rows (s)
    }
  } else {
    sel = 3;
    tA = bm; tB = bn;
    Ap = xA + (size_t)tA * 128 * K;
    Bp = wB + (size_t)tB * 128 * K;
  }

  // ---- staging: 4 GLDS16/wave/step; lane l -> row l>>2, chunk l&3 (16B)
  const int lrow = l >> 2;
  const int csrc = ((l & 3) ^ ((l >> 3) & 3)) * 8;
  const bf16* aS = Ap + (size_t)(wid * 32 + lrow) * K + csrc;
  const bf16* bS = Bp + (size_t)(wid * 32 + lrow) * K + csrc;

  auto stage = [&](int kt, char* base) {
    GLDS16(aS + kt, base + (wid * 32) * 64);
    GLDS16(aS + (size_t)16 * K + kt, base + (wid * 32 + 16) * 64);
    GLDS16(bS + kt, base + 8192 + (wid * 32) * 64);
    GLDS16(bS + (size_t)16 * K + kt, base + 8192 + (wid * 32 + 16) * 64);
  };

  // ---- loop-invariant LDS read offsets
  int offA[4], offB[4];
#pragma unroll
  for (int f = 0; f < 4; f++) {
    int ra = wm * 64 + f * 16 + (l & 15);
    offA[f] = ra * 64 + (((l >> 4) ^ ((ra >> 1) & 3)) * 16);
    int rb = wn * 64 + f * 16 + (l & 15);
    offB[f] = 8192 + rb * 64 + (((l >> 4) ^ ((rb >> 1) & 3)) * 16);
  }

  f32x4 acc[4][4] = {};

  char* cur = lds;
  char* nxt = lds + 16384;
  char* ovr = lds + 32768;
  stage(0, cur);
  stage(32, nxt);
#pragma unroll 1
  for (int t_ = 0; t_ < 32; ++t_) {
    if (t_ < 31) {
      asm volatile("s_waitcnt vmcnt(4)" ::: "memory");
    } else {
      asm volatile("s_waitcnt vmcnt(0)" ::: "memory");
    }
    __builtin_amdgcn_s_barrier();
    __builtin_amdgcn_sched_barrier(0);
    // stage AFTER the barrier: all waves' step-(t-1) reads of ovr are done.
    if (t_ + 2 < 32) stage((t_ + 2) * 32, ovr);

    bf16x8 af[4], bg[4];
#pragma unroll
    for (int f = 0; f < 4; f++) {
      af[f] = *(const bf16x8*)(cur + offA[f]);
      bg[f] = *(const bf16x8*)(cur + offB[f]);
    }
    __builtin_amdgcn_s_setprio(1);
#pragma unroll
    for (int mi = 0; mi < 4; mi++)
#pragma unroll
      for (int ni = 0; ni < 4; ni++)
        acc[mi][ni] = __builtin_amdgcn_mfma_f32_16x16x32_bf16(
            af[mi], bg[ni], acc[mi][ni], 0, 0, 0);
    __builtin_amdgcn_s_setprio(0);
    char* tmp = cur; cur = nxt; nxt = ovr; ovr = tmp;
  }

  if (MODE == 2) {   // wo: direct f32 stores (64 B segments, full lines)
    const int rbase = tA * 128 + wm * 64 + (l >> 4) * 4;
    const int cbase = tB * 128 + wn * 64 + (l & 15);
#pragma unroll
    for (int mi = 0; mi < 4; mi++)
#pragma unroll
      for (int ni = 0; ni < 4; ni++)
#pragma unroll
        for (int r = 0; r < 4; r++)
          outf[(size_t)(rbase + mi * 16 + r) * 1024 + cbase + ni * 16] =
              acc[mi][ni][r];
    return;
  }

  // ---- 2-pass half-tile epilogue via 64x272B overlay (ring is dead)
  __syncthreads();
#pragma unroll 1
  for (int pass = 0; pass < 2; ++pass) {
    if (wm == pass) {   // waves owning rows [pass*64, pass*64+64)
#pragma unroll
      for (int mi = 0; mi < 4; mi++)
#pragma unroll
        for (int ni = 0; ni < 4; ni++)
#pragma unroll
          for (int r = 0; r < 4; r++) {
            int rloc = mi * 16 + (l >> 4) * 4 + r;       // 0..63
            int col = wn * 64 + ni * 16 + (l & 15);      // 0..127
            *(bf16*)(lds + rloc * 272 + col * 2) = (bf16)acc[mi][ni][r];
          }
    }
    __syncthreads();
#pragma unroll 2
    for (int i = 0; i < 4; ++i) {
      const int id = t + 256 * i;
      const int rloc = id >> 4, ch = id & 15;
      bf16x8 v8 = *(const bf16x8*)(lds + rloc * 272 + ch * 16);
      const int row = pass * 64 + rloc;
      if (sel < 2) {
        const int m = tA * 128 + row;
        const int g = ch & 7;
        bf16x4 tc = *(const bf16x4*)(tabc + m * 32 + g * 4);
        bf16x4 tsn = *(const bf16x4*)(tabs + m * 32 + g * 4);
        bf16x8 o;
#pragma unroll
        for (int j = 0; j < 4; j++) {
          float cs = (float)tc[j], sn = (float)tsn[j];
          float e = (float)v8[2 * j], od = (float)v8[2 * j + 1];
          o[2 * j]     = (bf16)(e * cs - od * sn);
          o[2 * j + 1] = (bf16)(e * sn + od * cs);
        }
        bf16* dst = (sel == 0) ? oq : ok;
        const int h = tB * 2 + (ch >> 3);
        size_t idx = ((size_t)((m >> 11) * 16 + h) << 17) +
                     ((size_t)(m & 2047) << 6) + g * 8;
        *(bf16x8*)(dst + idx) = o;
      } else {
        const int dd = tA * 128 + row;
        const int h = dd >> 6;
        const int s0 = tB * 128 + ch * 8;
        size_t idx = ((size_t)((s0 >> 11) * 16 + h) << 17) +
                     ((size_t)(dd & 63) << 11) + (s0 & 2047);
        *(bf16x8*)(ov + idx) = v8;
      }
    }
    __syncthreads();
  }
}

// ---------------- causal flash attention, KVBLK=128 per barrier-pair --------
// (r12-proven) 512 blocks (one (bh,qt) each), 8 waves, QBLK=256. Each step
// stages TWO 64-kv sub-tiles; barriers per kv halved. Double-buffered (64 KB),
// counted vmcnt(4), 2 blocks/CU. Swapped QK^T; sigma-permuted in-register P;
// no max-subtract softmax.
__global__ __launch_bounds__(512, 4) void attn_k(const bf16* __restrict__ q,
                                                 const bf16* __restrict__ k,
                                                 const bf16* __restrict__ vt,
                                                 bf16* __restrict__ att) {
  __shared__ bf16 Ks[2][8192];   // [buf][sub*4096 + kv64 x d64], swizzled
  __shared__ bf16 Vs[2][8192];   // [buf][sub*4096 + d64 x kv64], swizzled

  const int t = threadIdx.x, l = t & 63, w = t >> 6;   // w = 0..7
  const int hi2 = l >> 5, q5 = l & 31;

  const int raw = blockIdx.x;
  const int r2 = raw & 255;
  const int wg = (r2 & 7) * 32 + (r2 >> 3);      // 4 bh per XCD, L2-local
  const int bh = ((raw < 256) ? 0 : 32) + (wg >> 3);
  const int qt = (raw < 256) ? (wg & 7) : 7 - (wg & 7);

  const bf16* qb = q + (size_t)bh * S * 64;
  const bf16* kb = k + (size_t)bh * S * 64;
  const bf16* vb = vt + (size_t)bh * 64 * S;

  const int lrow = l >> 3;
  const int clog = ((l & 7) ^ (lrow & 7)) * 8;   // pre-swizzled source chunk

  auto stage = [&](int st, int b) {
#pragma unroll
    for (int sub = 0; sub < 2; sub++) {
      const int nt = 2 * st + sub;
      GLDS16(kb + (size_t)(nt * 64 + w * 8 + lrow) * 64 + clog,
             &Ks[b][sub * 4096 + w * 512]);
      GLDS16(vb + (size_t)(w * 8 + lrow) * S + nt * 64 + clog,
             &Vs[b][sub * 4096 + w * 512]);
    }
  };

  const int swz = (q5 & 7) << 4;
  int kaddr[4], vaddr[8];
#pragma unroll
  for (int c = 0; c < 4; c++)
    kaddr[c] = q5 * 128 + ((32 * c + 16 * hi2) ^ swz);
#pragma unroll
  for (int m = 0; m < 8; m++)
    vaddr[m] = q5 * 128 + ((16 * m) ^ swz) + 8 * hi2;

  const int b_ = bh >> 4, h_ = bh & 15;
  const char* KsB = (const char*)&Ks[0][0];
  const char* VsB = (const char*)&Vs[0][0];

  const int wqbase = qt * 256 + w * 32;
  const int qrow = wqbase + q5;
  bf16x8 qf[4];   // Q^T B-operand, chunk c: d = 16c+8*hi2+(0..7); scaled
#pragma unroll
  for (int c = 0; c < 4; c++) {
    bf16x8 rq = *(const bf16x8*)&qb[(size_t)qrow * 64 + 16 * c + 8 * hi2];
    bf16x8 s_;
#pragma unroll
    for (int j2 = 0; j2 < 8; j2++)
      s_[j2] = (bf16)((float)rq[j2] * 0.18033688011112042f);
    qf[c] = s_;
  }

  f32x16 acc[2] = {};
  float l_r = 0.f;
  const int nst = 2 * qt + 2;            // steps of 128 kv
  const int qmaxw = wqbase + 31;

  stage(0, 0);
#pragma unroll 1
  for (int s = 0; s < nst; ++s) {
    if (s + 1 < nst) {
      stage(s + 1, (s + 1) & 1);
      asm volatile("s_waitcnt vmcnt(4)" ::: "memory");
    } else {
      asm volatile("s_waitcnt vmcnt(0)" ::: "memory");
    }
    __builtin_amdgcn_s_barrier();
    __builtin_amdgcn_sched_barrier(0);

    const int bo_buf = (s & 1) * 16384;
    float rs = 0.f;
#pragma unroll
    for (int sub = 0; sub < 2; sub++) {
      const int nt = 2 * s + sub;
      if (64 * nt > qmaxw) continue;     // wave-uniform causal gate
      const int bo = bo_buf + sub * 8192;
#pragma unroll
      for (int T = 0; T < 2; T++) {
        // S^T = K Q^T for half-tile T (kv 32T..32T+31 within sub)
        f32x16 sc = {};
        __builtin_amdgcn_s_setprio(1);
#pragma unroll
        for (int c = 0; c < 4; c++) {
          bf16x8 kf = *(const bf16x8*)(KsB + bo + T * 4096 + kaddr[c]);
          sc = __builtin_amdgcn_mfma_f32_32x32x16_bf16(kf, qf[c], sc, 0, 0, 0);
        }
        __builtin_amdgcn_s_setprio(0);

        if (64 * nt + 32 * T + 31 > wqbase) {   // causal mask
#pragma unroll
          for (int r = 0; r < 16; r++) {
            int kvg = 64 * nt + 32 * T + (r & 3) + 8 * (r >> 2) + 4 * hi2;
            if (kvg > qrow) sc[r] = -1e30f;
          }
        }

        // softmax (no max-subtract) + pack P for this half
        bf16x8 pa0, pa1;
#pragma unroll
        for (int r = 0; r < 8; r++) {
          float p0 = __builtin_amdgcn_exp2f(sc[r]);
          float p1 = __builtin_amdgcn_exp2f(sc[8 + r]);
          rs += p0 + p1;
          pa0[r] = (bf16)p0;
          pa1[r] = (bf16)p1;
        }

        // O += P'V for this half
        __builtin_amdgcn_s_setprio(1);
#pragma unroll
        for (int dt = 0; dt < 2; dt++) {
          bf16x4 v0 = *(const bf16x4*)(VsB + bo + dt * 4096 + vaddr[4 * T]);
          bf16x4 v1 = *(const bf16x4*)(VsB + bo + dt * 4096 + vaddr[4 * T + 1]);
          bf16x8 bv;
#pragma unroll
          for (int j2 = 0; j2 < 4; j2++) { bv[j2] = v0[j2]; bv[4 + j2] = v1[j2]; }
          acc[dt] = __builtin_amdgcn_mfma_f32_32x32x16_bf16(pa0, bv, acc[dt], 0, 0, 0);
          v0 = *(const bf16x4*)(VsB + bo + dt * 4096 + vaddr[4 * T + 2]);
          v1 = *(const bf16x4*)(VsB + bo + dt * 4096 + vaddr[4 * T + 3]);
#pragma unroll
          for (int j2 = 0; j2 < 4; j2++) { bv[j2] = v0[j2]; bv[4 + j2] = v1[j2]; }
          acc[dt] = __builtin_amdgcn_mfma_f32_32x32x16_bf16(pa1, bv, acc[dt], 0, 0, 0);
        }
        __builtin_amdgcn_s_setprio(0);
      }
    }
    rs += __shfl_xor(rs, 32);
    l_r += rs;

    asm volatile("s_waitcnt lgkmcnt(0)" ::: "memory");
    __builtin_amdgcn_sched_barrier(0);
    __builtin_amdgcn_s_barrier();
  }

  // epilogue: O row = qt*256 + w*32 + rmap(r,hi2), col d = 32dt + q5
  float linv = 1.f / l_r;
#pragma unroll
  for (int r = 0; r < 16; r++) {
    int rmap = (r & 3) + 8 * (r >> 2) + 4 * hi2;
    float li = __shfl(linv, rmap);
    int rowq = wqbase + rmap;
    size_t rb = ((size_t)(b_ * S + rowq) << 10) + h_ * 64 + q5;
#pragma unroll
    for (int dt = 0; dt < 2; dt++)
      att[rb + 32 * dt] = (bf16)(acc[dt][r] * li);
  }
}

extern "C" void kernel_launch(void* const* d_in, const int* in_sizes, int n_in,
                              void* d_out, int out_size, void* d_ws, size_t ws_size,
                              hipStream_t stream) {
  const float* x  = (const float*)d_in[0];
  const int* tp   = (const int*)d_in[1];
  const float* wq = (const float*)d_in[2];
  const float* wk = (const float*)d_in[3];
  const float* wv = (const float*)d_in[4];
  const float* wo = (const float*)d_in[5];
  float* out = (float*)d_out;

  char* ws = (char*)d_ws;
  const size_t TEN = 16777216;  // 8192*1024*2 bytes
  bf16* x_bf    = (bf16*)(ws);
  bf16* q_bf    = (bf16*)(ws + TEN);
  bf16* k_bf    = (bf16*)(ws + 2 * TEN);
  bf16* v_bf    = (bf16*)(ws + 3 * TEN);
  bf16* wqkv_bf = (bf16*)(ws + 4 * TEN);          // 3072x1024 = 6MB
  bf16* wo_bf   = wqkv_bf + 3 * 1048576;          // 2MB
  bf16* tabc    = wo_bf + 1048576;                // 512KB (8192x32 bf16)
  bf16* tabs    = tabc + 262144;                  // 512KB
  bf16* att_bf  = x_bf;   // alias: x_bf dead after QKV projection

  cvt_all<<<7168, 256, 0, stream>>>(x, wq, wk, wv, wo, tp, x_bf, wqkv_bf,
                                    wo_bf, tabc, tabs);

  dim3 gq(64, 24);
  gemm_k<0><<<gq, 256, 0, stream>>>(x_bf, wqkv_bf, tabc, tabs, q_bf, k_bf,
                                    v_bf, nullptr);

  attn_k<<<512, 512, 0, stream>>>(q_bf, k_bf, v_bf, att_bf);

  dim3 go(64, 8);
  gemm_k<2><<<go, 256, 0, stream>>>(att_bf, wo_bf, nullptr, nullptr, nullptr,
                                    nullptr, nullptr, out);
}